// Round 1
// baseline (367.216 us; speedup 1.0000x reference)
//
#include <hip/hip_runtime.h>
#include <hip/hip_bf16.h>

// GCN 2-layer: h1 = relu(Ahat (x@W1) + b1); out = softmax(relu(Ahat (h1@W2) + b2))
// Ahat = D^-1/2 (A + I) D^-1/2, edges dst<-src, deg over dst incl self-loops.

__global__ void k_zero(int* __restrict__ p, int n) {
    int i = blockIdx.x * blockDim.x + threadIdx.x;
    if (i < n) p[i] = 0;
}

__global__ void k_deg(const int* __restrict__ dst, int E, int* __restrict__ deg) {
    int e = blockIdx.x * blockDim.x + threadIdx.x;
    if (e < E) atomicAdd(&deg[dst[e]], 1);
}

// block-level exclusive scan (chunk = 256)
__global__ void k_scan1(const int* __restrict__ deg, int* __restrict__ rowstart,
                        int* __restrict__ partials, int N) {
    __shared__ int s[256];
    int t = threadIdx.x;
    int i = blockIdx.x * 256 + t;
    int v = (i < N) ? deg[i] : 0;
    s[t] = v;
    __syncthreads();
    for (int off = 1; off < 256; off <<= 1) {
        int tmp = (t >= off) ? s[t - off] : 0;
        __syncthreads();
        s[t] += tmp;
        __syncthreads();
    }
    if (i < N) rowstart[i] = s[t] - v;          // exclusive
    if (t == 255) partials[blockIdx.x] = s[t];  // block total
}

__global__ void k_scan2(int* __restrict__ partials, int NB) {
    __shared__ int s[512];
    int t = threadIdx.x;
    int v = (t < NB) ? partials[t] : 0;
    s[t] = v;
    __syncthreads();
    for (int off = 1; off < 512; off <<= 1) {
        int tmp = (t >= off) ? s[t - off] : 0;
        __syncthreads();
        s[t] += tmp;
        __syncthreads();
    }
    if (t < NB) partials[t] = s[t] - v;  // exclusive over block totals
}

__global__ void k_scan3(const int* __restrict__ deg, int* __restrict__ rowstart,
                        const int* __restrict__ partials, int* __restrict__ cursor,
                        float* __restrict__ dinv, int N) {
    int i = blockIdx.x * 256 + threadIdx.x;
    if (i < N) {
        int rs = rowstart[i] + partials[blockIdx.x];
        rowstart[i] = rs;
        cursor[i] = rs;
        dinv[i] = rsqrtf((float)(deg[i] + 1));  // +1 self loop, always > 0
    }
}

__global__ void k_fill(const int* __restrict__ ei, int E, int* __restrict__ cursor,
                       int* __restrict__ csr) {
    int e = blockIdx.x * blockDim.x + threadIdx.x;
    if (e < E) {
        int s = ei[e];       // src
        int d = ei[E + e];   // dst
        int pos = atomicAdd(&cursor[d], 1);
        csr[pos] = s;
    }
}

// h1[N][48] = x[N][128] @ W1[128][48], f32, LDS tiled, 4x4 register blocking
#define G1_BM 64
__global__ __launch_bounds__(192) void k_gemm1(const float* __restrict__ x,
                                               const float* __restrict__ W1,
                                               float* __restrict__ h1, int N) {
    __shared__ float xs[G1_BM * 132];  // rows stride 132 (16B aligned, bank-spread)
    __shared__ float wt[48 * 132];     // W1 transposed: wt[c][k]
    int t = threadIdx.x;
    int r0 = blockIdx.x * G1_BM;

    for (int i = t; i < 128 * 48; i += 192) {
        int k = i / 48, c = i % 48;
        wt[c * 132 + k] = W1[i];
    }
    for (int i = t; i < G1_BM * 32; i += 192) {  // 32 float4 per row
        int r = i >> 5, kq = i & 31;
        float4 v;
        if (r0 + r < N) v = *(const float4*)(x + (size_t)(r0 + r) * 128 + kq * 4);
        else v = make_float4(0.f, 0.f, 0.f, 0.f);
        *(float4*)(xs + r * 132 + kq * 4) = v;
    }
    __syncthreads();

    int cg = t % 12;  // col group: cols cg*4 .. +3
    int rg = t / 12;  // row group: rows rg*4 .. +3  (0..15)
    float acc[4][4] = {};
    const float* xa = xs + (rg * 4) * 132;
    const float* wb = wt + (cg * 4) * 132;

    for (int kk = 0; kk < 128; kk += 4) {
        float4 A[4], B[4];
#pragma unroll
        for (int i = 0; i < 4; i++) A[i] = *(const float4*)(xa + i * 132 + kk);
#pragma unroll
        for (int j = 0; j < 4; j++) B[j] = *(const float4*)(wb + j * 132 + kk);
#pragma unroll
        for (int i = 0; i < 4; i++)
#pragma unroll
            for (int j = 0; j < 4; j++)
                acc[i][j] += A[i].x * B[j].x + A[i].y * B[j].y +
                             A[i].z * B[j].z + A[i].w * B[j].w;
    }

#pragma unroll
    for (int i = 0; i < 4; i++) {
        int r = r0 + rg * 4 + i;
        if (r < N) {
            float4 o = make_float4(acc[i][0], acc[i][1], acc[i][2], acc[i][3]);
            *(float4*)(h1 + (size_t)r * 48 + cg * 4) = o;
        }
    }
}

// layer-1 aggregation: one wave per node, 48 feature lanes, relu fused
__global__ __launch_bounds__(256) void k_agg1(const float* __restrict__ h1,
                                              const int* __restrict__ csr,
                                              const int* __restrict__ rowstart,
                                              const int* __restrict__ deg,
                                              const float* __restrict__ dinv,
                                              const float* __restrict__ b1,
                                              float* __restrict__ r1, int N) {
    int wave = threadIdx.x >> 6;
    int lane = threadIdx.x & 63;
    int v = blockIdx.x * 4 + wave;
    if (v >= N) return;
    int f = lane < 48 ? lane : 47;  // lanes 48..63 duplicate lane 47 (masked at store)

    int start = rowstart[v];
    int d = deg[v];
    float dv = dinv[v];
    const int* cs = csr + start;
    float acc = 0.f;
    int e = 0;
    for (; e + 4 <= d; e += 4) {  // 4 independent chains for MLP
        int s0 = cs[e], s1 = cs[e + 1], s2 = cs[e + 2], s3 = cs[e + 3];
        float w0 = dinv[s0], w1 = dinv[s1], w2 = dinv[s2], w3 = dinv[s3];
        float v0 = h1[(size_t)s0 * 48 + f];
        float v1 = h1[(size_t)s1 * 48 + f];
        float v2 = h1[(size_t)s2 * 48 + f];
        float v3 = h1[(size_t)s3 * 48 + f];
        acc += w0 * v0;
        acc += w1 * v1;
        acc += w2 * v2;
        acc += w3 * v3;
    }
    for (; e < d; ++e) {
        int s = cs[e];
        acc += dinv[s] * h1[(size_t)s * 48 + f];
    }
    float self = h1[(size_t)v * 48 + f];
    float out = dv * acc + dv * dv * self + b1[f];
    out = fmaxf(out, 0.f);
    if (lane < 48) r1[(size_t)v * 48 + lane] = out;
}

// h2[N][16] = r1[N][48] @ W2[48][16]; bias applied later in agg2
__global__ __launch_bounds__(256) void k_gemm2(const float* __restrict__ r1,
                                               const float* __restrict__ W2,
                                               float* __restrict__ h2, int N) {
    __shared__ float w2s[48 * 16];
    int t = threadIdx.x;
    for (int i = t; i < 768; i += 256) w2s[i] = W2[i];
    __syncthreads();
    int flat = blockIdx.x * 256 + t;
    int row = flat >> 2;
    int cg = (flat & 3) * 4;
    if (row >= N) return;
    float4 acc = make_float4(0.f, 0.f, 0.f, 0.f);
    const float* xr = r1 + (size_t)row * 48;
    for (int kk = 0; kk < 48; kk += 4) {
        float4 a = *(const float4*)(xr + kk);
#pragma unroll
        for (int j = 0; j < 4; j++) {
            float av = (j == 0) ? a.x : (j == 1) ? a.y : (j == 2) ? a.z : a.w;
            float4 b = *(const float4*)(w2s + (kk + j) * 16 + cg);
            acc.x += av * b.x;
            acc.y += av * b.y;
            acc.z += av * b.z;
            acc.w += av * b.w;
        }
    }
    *(float4*)(h2 + (size_t)row * 16 + cg) = acc;
}

// layer-2 aggregation + bias + relu + 16-wide softmax. 4 nodes per wave.
__global__ __launch_bounds__(256) void k_agg2(const float* __restrict__ h2,
                                              const int* __restrict__ csr,
                                              const int* __restrict__ rowstart,
                                              const int* __restrict__ deg,
                                              const float* __restrict__ dinv,
                                              const float* __restrict__ b2,
                                              float* __restrict__ out, int N) {
    int tid = threadIdx.x;
    int lane = tid & 63;
    int g = lane >> 4;   // node sub-group within wave
    int f = lane & 15;   // feature
    int v = blockIdx.x * 16 + (tid >> 6) * 4 + g;
    if (v >= N) return;

    int start = rowstart[v];
    int d = deg[v];
    float dv = dinv[v];
    const int* cs = csr + start;
    float acc = 0.f;
    int e = 0;
    for (; e + 4 <= d; e += 4) {
        int s0 = cs[e], s1 = cs[e + 1], s2 = cs[e + 2], s3 = cs[e + 3];
        float w0 = dinv[s0], w1 = dinv[s1], w2 = dinv[s2], w3 = dinv[s3];
        acc += w0 * h2[(size_t)s0 * 16 + f];
        acc += w1 * h2[(size_t)s1 * 16 + f];
        acc += w2 * h2[(size_t)s2 * 16 + f];
        acc += w3 * h2[(size_t)s3 * 16 + f];
    }
    for (; e < d; ++e) {
        int s = cs[e];
        acc += dinv[s] * h2[(size_t)s * 16 + f];
    }
    float z = dv * acc + dv * dv * h2[(size_t)v * 16 + f] + b2[f];
    z = fmaxf(z, 0.f);

    // softmax over the 16 lanes of this group (xor masks 1,2,4,8 stay in-group)
    float m = z;
    m = fmaxf(m, __shfl_xor(m, 1));
    m = fmaxf(m, __shfl_xor(m, 2));
    m = fmaxf(m, __shfl_xor(m, 4));
    m = fmaxf(m, __shfl_xor(m, 8));
    float p = __expf(z - m);
    float ssum = p;
    ssum += __shfl_xor(ssum, 1);
    ssum += __shfl_xor(ssum, 2);
    ssum += __shfl_xor(ssum, 4);
    ssum += __shfl_xor(ssum, 8);
    out[(size_t)v * 16 + f] = p / ssum;
}

extern "C" void kernel_launch(void* const* d_in, const int* in_sizes, int n_in,
                              void* d_out, int out_size, void* d_ws, size_t ws_size,
                              hipStream_t stream) {
    const float* x  = (const float*)d_in[0];
    const int*   ei = (const int*)d_in[1];
    const float* W1 = (const float*)d_in[2];
    const float* b1 = (const float*)d_in[3];
    const float* W2 = (const float*)d_in[4];
    const float* b2 = (const float*)d_in[5];
    float* out = (float*)d_out;

    int N = in_sizes[0] / 128;
    int E = in_sizes[1] / 2;

    char* p = (char*)d_ws;
    auto alloc = [&](size_t bytes) -> char* {
        char* q = p;
        p += (bytes + 255) & ~(size_t)255;
        return q;
    };
    int*   deg      = (int*)alloc((size_t)N * 4);
    int*   rowstart = (int*)alloc((size_t)N * 4);
    int*   cursor   = (int*)alloc((size_t)N * 4);
    float* dinv     = (float*)alloc((size_t)N * 4);
    int*   partials = (int*)alloc(4096);
    int*   csr      = (int*)alloc((size_t)E * 4);
    float* h1       = (float*)alloc((size_t)N * 48 * 4);
    float* r1       = (float*)alloc((size_t)N * 48 * 4);
    float* h2       = h1;  // h1 dead after k_agg1; reuse for h2

    int NB = (N + 255) / 256;

    hipLaunchKernelGGL(k_zero, dim3(NB), dim3(256), 0, stream, deg, N);
    hipLaunchKernelGGL(k_deg, dim3((E + 255) / 256), dim3(256), 0, stream, ei + E, E, deg);
    hipLaunchKernelGGL(k_scan1, dim3(NB), dim3(256), 0, stream, deg, rowstart, partials, N);
    hipLaunchKernelGGL(k_scan2, dim3(1), dim3(512), 0, stream, partials, NB);
    hipLaunchKernelGGL(k_scan3, dim3(NB), dim3(256), 0, stream, deg, rowstart, partials,
                       cursor, dinv, N);
    hipLaunchKernelGGL(k_fill, dim3((E + 255) / 256), dim3(256), 0, stream, ei, E, cursor, csr);
    hipLaunchKernelGGL(k_gemm1, dim3((N + G1_BM - 1) / G1_BM), dim3(192), 0, stream,
                       x, W1, h1, N);
    hipLaunchKernelGGL(k_agg1, dim3((N + 3) / 4), dim3(256), 0, stream,
                       h1, csr, rowstart, deg, dinv, b1, r1, N);
    hipLaunchKernelGGL(k_gemm2, dim3((N * 4 + 255) / 256), dim3(256), 0, stream, r1, W2, h2, N);
    hipLaunchKernelGGL(k_agg2, dim3((N + 15) / 16), dim3(256), 0, stream,
                       h2, csr, rowstart, deg, dinv, b2, out, N);
}

// Round 2
// 269.225 us; speedup vs baseline: 1.3640x; 1.3640x over previous
//
#include <hip/hip_runtime.h>
#include <hip/hip_bf16.h>

// GCN 2-layer: h1 = relu(Ahat (x@W1) + b1); out = softmax(relu(Ahat (h1@W2) + b2))
// Ahat = D^-1/2 (A + I) D^-1/2.
// CSR build via bucketed counting sort (bucket = dst>>8) — no global atomics,
// all scattered writes confined to single-workgroup (single-XCD) regions so
// L2 coalesces them into full-line writebacks (k_fill was 105MB WRITE_SIZE for
// 6.4MB of data at 828 GB/s = 139us).

#define TILE 8192  // edges per histogram/scatter workgroup (256 thr x 32)

// per-tile bucket histogram -> Hw[tile][nbuck]
__global__ __launch_bounds__(256) void k_bhist(const int* __restrict__ dst, int E,
                                               int* __restrict__ Hw, int nbuck) {
    __shared__ int h[512];
    int t = threadIdx.x;
    for (int i = t; i < nbuck; i += 256) h[i] = 0;
    __syncthreads();
    int base = blockIdx.x * TILE;
#pragma unroll
    for (int r = 0; r < TILE / 256; ++r) {
        int e = base + r * 256 + t;
        if (e < E) atomicAdd(&h[dst[e] >> 8], 1);
    }
    __syncthreads();
    for (int i = t; i < nbuck; i += 256) Hw[blockIdx.x * nbuck + i] = h[i];
}

// single WG: bucket totals -> exclusive bucket starts; then turn Hw columns
// into per-(tile,bucket) global offsets.  nbuck <= 512 for N <= 131072.
__global__ __launch_bounds__(512) void k_bscan(int* __restrict__ Hw, int nTiles,
                                               int nbuck, int* __restrict__ bstart) {
    __shared__ int s[512];
    int t = threadIdx.x;
    int total = 0;
    if (t < nbuck)
        for (int tt = 0; tt < nTiles; ++tt) total += Hw[tt * nbuck + t];
    s[t] = total;
    __syncthreads();
    for (int off = 1; off < 512; off <<= 1) {
        int tmp = (t >= off) ? s[t - off] : 0;
        __syncthreads();
        s[t] += tmp;
        __syncthreads();
    }
    int excl = s[t] - total;
    if (t < nbuck) bstart[t] = excl;
    if (t == nbuck - 1) bstart[nbuck] = s[t];  // = E
    __syncthreads();
    if (t < nbuck) {
        int running = excl;
        for (int tt = 0; tt < nTiles; ++tt) {
            int v = Hw[tt * nbuck + t];
            Hw[tt * nbuck + t] = running;
            running += v;
        }
    }
}

// scatter edges into bucket-grouped ebuf; per-(tile,bucket) runs are
// contiguous and single-writer -> coalesced writebacks.
__global__ __launch_bounds__(256) void k_bscatter(const int* __restrict__ ei, int E,
                                                  const int* __restrict__ Hw, int nbuck,
                                                  int2* __restrict__ ebuf) {
    __shared__ int cur[512];
    int t = threadIdx.x;
    for (int i = t; i < nbuck; i += 256) cur[i] = Hw[blockIdx.x * nbuck + i];
    __syncthreads();
    int base = blockIdx.x * TILE;
#pragma unroll
    for (int r = 0; r < TILE / 256; ++r) {
        int e = base + r * 256 + t;
        if (e < E) {
            int s = ei[e];
            int d = ei[E + e];
            int pos = atomicAdd(&cur[d >> 8], 1);
            ebuf[pos] = make_int2(s, d);
        }
    }
}

// one WG per bucket (256 nodes): derive deg/rowstart/dinv + fill csr.
// csr writes land in this bucket's contiguous ~16KB slice (one XCD).
__global__ __launch_bounds__(256) void k_csrfill(const int2* __restrict__ ebuf,
                                                 const int* __restrict__ bstart,
                                                 int* __restrict__ csr,
                                                 int* __restrict__ rowstart,
                                                 int* __restrict__ deg,
                                                 float* __restrict__ dinv, int N) {
    __shared__ int lcnt[256];
    __shared__ int lscan[256];
    __shared__ int lcur[256];
    int t = threadIdx.x;
    int nodebase = blockIdx.x << 8;
    int segs = bstart[blockIdx.x];
    int sege = bstart[blockIdx.x + 1];
    lcnt[t] = 0;
    __syncthreads();
    for (int i = segs + t; i < sege; i += 256)
        atomicAdd(&lcnt[ebuf[i].y & 255], 1);
    __syncthreads();
    int v = lcnt[t];
    lscan[t] = v;
    __syncthreads();
    for (int off = 1; off < 256; off <<= 1) {
        int tmp = (t >= off) ? lscan[t - off] : 0;
        __syncthreads();
        lscan[t] += tmp;
        __syncthreads();
    }
    int excl = lscan[t] - v;
    int node = nodebase + t;
    if (node < N) {
        rowstart[node] = segs + excl;
        deg[node] = v;
        dinv[node] = rsqrtf((float)(v + 1));  // +1 self loop
    }
    lcur[t] = segs + excl;
    __syncthreads();
    for (int i = segs + t; i < sege; i += 256) {
        int2 e = ebuf[i];
        int pos = atomicAdd(&lcur[e.y & 255], 1);
        csr[pos] = e.x;
    }
}

// h1[N][48] = x[N][128] @ W1[128][48], f32, LDS tiled, 4x4 register blocking
#define G1_BM 64
__global__ __launch_bounds__(192) void k_gemm1(const float* __restrict__ x,
                                               const float* __restrict__ W1,
                                               float* __restrict__ h1, int N) {
    __shared__ float xs[G1_BM * 132];
    __shared__ float wt[48 * 132];
    int t = threadIdx.x;
    int r0 = blockIdx.x * G1_BM;

    for (int i = t; i < 128 * 48; i += 192) {
        int k = i / 48, c = i % 48;
        wt[c * 132 + k] = W1[i];
    }
    for (int i = t; i < G1_BM * 32; i += 192) {
        int r = i >> 5, kq = i & 31;
        float4 v;
        if (r0 + r < N) v = *(const float4*)(x + (size_t)(r0 + r) * 128 + kq * 4);
        else v = make_float4(0.f, 0.f, 0.f, 0.f);
        *(float4*)(xs + r * 132 + kq * 4) = v;
    }
    __syncthreads();

    int cg = t % 12;
    int rg = t / 12;
    float acc[4][4] = {};
    const float* xa = xs + (rg * 4) * 132;
    const float* wb = wt + (cg * 4) * 132;

    for (int kk = 0; kk < 128; kk += 4) {
        float4 A[4], B[4];
#pragma unroll
        for (int i = 0; i < 4; i++) A[i] = *(const float4*)(xa + i * 132 + kk);
#pragma unroll
        for (int j = 0; j < 4; j++) B[j] = *(const float4*)(wb + j * 132 + kk);
#pragma unroll
        for (int i = 0; i < 4; i++)
#pragma unroll
            for (int j = 0; j < 4; j++)
                acc[i][j] += A[i].x * B[j].x + A[i].y * B[j].y +
                             A[i].z * B[j].z + A[i].w * B[j].w;
    }

#pragma unroll
    for (int i = 0; i < 4; i++) {
        int r = r0 + rg * 4 + i;
        if (r < N) {
            float4 o = make_float4(acc[i][0], acc[i][1], acc[i][2], acc[i][3]);
            *(float4*)(h1 + (size_t)r * 48 + cg * 4) = o;
        }
    }
}

// layer-1 aggregation: one wave per node, 48 feature lanes, relu fused
__global__ __launch_bounds__(256) void k_agg1(const float* __restrict__ h1,
                                              const int* __restrict__ csr,
                                              const int* __restrict__ rowstart,
                                              const int* __restrict__ deg,
                                              const float* __restrict__ dinv,
                                              const float* __restrict__ b1,
                                              float* __restrict__ r1, int N) {
    int wave = threadIdx.x >> 6;
    int lane = threadIdx.x & 63;
    int v = blockIdx.x * 4 + wave;
    if (v >= N) return;
    int f = lane < 48 ? lane : 47;

    int start = rowstart[v];
    int d = deg[v];
    float dv = dinv[v];
    const int* cs = csr + start;
    float acc = 0.f;
    int e = 0;
    for (; e + 4 <= d; e += 4) {
        int s0 = cs[e], s1 = cs[e + 1], s2 = cs[e + 2], s3 = cs[e + 3];
        float w0 = dinv[s0], w1 = dinv[s1], w2 = dinv[s2], w3 = dinv[s3];
        float v0 = h1[(size_t)s0 * 48 + f];
        float v1 = h1[(size_t)s1 * 48 + f];
        float v2 = h1[(size_t)s2 * 48 + f];
        float v3 = h1[(size_t)s3 * 48 + f];
        acc += w0 * v0;
        acc += w1 * v1;
        acc += w2 * v2;
        acc += w3 * v3;
    }
    for (; e < d; ++e) {
        int s = cs[e];
        acc += dinv[s] * h1[(size_t)s * 48 + f];
    }
    float self = h1[(size_t)v * 48 + f];
    float out = dv * acc + dv * dv * self + b1[f];
    out = fmaxf(out, 0.f);
    if (lane < 48) r1[(size_t)v * 48 + lane] = out;
}

// h2[N][16] = r1[N][48] @ W2[48][16]
__global__ __launch_bounds__(256) void k_gemm2(const float* __restrict__ r1,
                                               const float* __restrict__ W2,
                                               float* __restrict__ h2, int N) {
    __shared__ float w2s[48 * 16];
    int t = threadIdx.x;
    for (int i = t; i < 768; i += 256) w2s[i] = W2[i];
    __syncthreads();
    int flat = blockIdx.x * 256 + t;
    int row = flat >> 2;
    int cg = (flat & 3) * 4;
    if (row >= N) return;
    float4 acc = make_float4(0.f, 0.f, 0.f, 0.f);
    const float* xr = r1 + (size_t)row * 48;
    for (int kk = 0; kk < 48; kk += 4) {
        float4 a = *(const float4*)(xr + kk);
#pragma unroll
        for (int j = 0; j < 4; j++) {
            float av = (j == 0) ? a.x : (j == 1) ? a.y : (j == 2) ? a.z : a.w;
            float4 b = *(const float4*)(w2s + (kk + j) * 16 + cg);
            acc.x += av * b.x;
            acc.y += av * b.y;
            acc.z += av * b.z;
            acc.w += av * b.w;
        }
    }
    *(float4*)(h2 + (size_t)row * 16 + cg) = acc;
}

// layer-2 aggregation + bias + relu + 16-wide softmax. 4 nodes per wave.
__global__ __launch_bounds__(256) void k_agg2(const float* __restrict__ h2,
                                              const int* __restrict__ csr,
                                              const int* __restrict__ rowstart,
                                              const int* __restrict__ deg,
                                              const float* __restrict__ dinv,
                                              const float* __restrict__ b2,
                                              float* __restrict__ out, int N) {
    int tid = threadIdx.x;
    int lane = tid & 63;
    int g = lane >> 4;
    int f = lane & 15;
    int v = blockIdx.x * 16 + (tid >> 6) * 4 + g;
    if (v >= N) return;

    int start = rowstart[v];
    int d = deg[v];
    float dv = dinv[v];
    const int* cs = csr + start;
    float acc = 0.f;
    int e = 0;
    for (; e + 4 <= d; e += 4) {
        int s0 = cs[e], s1 = cs[e + 1], s2 = cs[e + 2], s3 = cs[e + 3];
        float w0 = dinv[s0], w1 = dinv[s1], w2 = dinv[s2], w3 = dinv[s3];
        acc += w0 * h2[(size_t)s0 * 16 + f];
        acc += w1 * h2[(size_t)s1 * 16 + f];
        acc += w2 * h2[(size_t)s2 * 16 + f];
        acc += w3 * h2[(size_t)s3 * 16 + f];
    }
    for (; e < d; ++e) {
        int s = cs[e];
        acc += dinv[s] * h2[(size_t)s * 16 + f];
    }
    float z = dv * acc + dv * dv * h2[(size_t)v * 16 + f] + b2[f];
    z = fmaxf(z, 0.f);

    float m = z;
    m = fmaxf(m, __shfl_xor(m, 1));
    m = fmaxf(m, __shfl_xor(m, 2));
    m = fmaxf(m, __shfl_xor(m, 4));
    m = fmaxf(m, __shfl_xor(m, 8));
    float p = __expf(z - m);
    float ssum = p;
    ssum += __shfl_xor(ssum, 1);
    ssum += __shfl_xor(ssum, 2);
    ssum += __shfl_xor(ssum, 4);
    ssum += __shfl_xor(ssum, 8);
    out[(size_t)v * 16 + f] = p / ssum;
}

extern "C" void kernel_launch(void* const* d_in, const int* in_sizes, int n_in,
                              void* d_out, int out_size, void* d_ws, size_t ws_size,
                              hipStream_t stream) {
    const float* x  = (const float*)d_in[0];
    const int*   ei = (const int*)d_in[1];
    const float* W1 = (const float*)d_in[2];
    const float* b1 = (const float*)d_in[3];
    const float* W2 = (const float*)d_in[4];
    const float* b2 = (const float*)d_in[5];
    float* out = (float*)d_out;

    int N = in_sizes[0] / 128;
    int E = in_sizes[1] / 2;
    int NBK = (N + 255) >> 8;
    int nTiles = (E + TILE - 1) / TILE;

    char* p = (char*)d_ws;
    auto alloc = [&](size_t bytes) -> char* {
        char* q = p;
        p += (bytes + 255) & ~(size_t)255;
        return q;
    };
    int*   deg      = (int*)alloc((size_t)N * 4);
    int*   rowstart = (int*)alloc((size_t)N * 4);
    float* dinv     = (float*)alloc((size_t)N * 4);
    int*   bstart   = (int*)alloc((size_t)(NBK + 1) * 4);
    int*   Hw       = (int*)alloc((size_t)nTiles * NBK * 4);
    int*   csr      = (int*)alloc((size_t)E * 4);
    // ebuf (E*8 = 12.8MB) dead after k_csrfill; h1 (N*48*4 = 19.2MB) overlays it.
    char*  ovl      = alloc((size_t)N * 48 * 4 > (size_t)E * 8 ? (size_t)N * 48 * 4
                                                               : (size_t)E * 8);
    int2*  ebuf     = (int2*)ovl;
    float* h1       = (float*)ovl;
    float* r1       = (float*)alloc((size_t)N * 48 * 4);
    float* h2       = h1;  // h1 dead after k_agg1

    hipLaunchKernelGGL(k_bhist, dim3(nTiles), dim3(256), 0, stream, ei + E, E, Hw, NBK);
    hipLaunchKernelGGL(k_bscan, dim3(1), dim3(512), 0, stream, Hw, nTiles, NBK, bstart);
    hipLaunchKernelGGL(k_bscatter, dim3(nTiles), dim3(256), 0, stream, ei, E, Hw, NBK, ebuf);
    hipLaunchKernelGGL(k_csrfill, dim3(NBK), dim3(256), 0, stream,
                       ebuf, bstart, csr, rowstart, deg, dinv, N);
    hipLaunchKernelGGL(k_gemm1, dim3((N + G1_BM - 1) / G1_BM), dim3(192), 0, stream,
                       x, W1, h1, N);
    hipLaunchKernelGGL(k_agg1, dim3((N + 3) / 4), dim3(256), 0, stream,
                       h1, csr, rowstart, deg, dinv, b1, r1, N);
    hipLaunchKernelGGL(k_gemm2, dim3((N * 4 + 255) / 256), dim3(256), 0, stream, r1, W2, h2, N);
    hipLaunchKernelGGL(k_agg2, dim3((N + 15) / 16), dim3(256), 0, stream,
                       h2, csr, rowstart, deg, dinv, b2, out, N);
}

// Round 3
// 243.797 us; speedup vs baseline: 1.5062x; 1.1043x over previous
//
#include <hip/hip_runtime.h>
#include <hip/hip_bf16.h>
#include <hip/hip_fp16.h>

// GCN 2-layer: h1 = relu(Ahat (x@W1) + b1); out = softmax(relu(Ahat (h1@W2) + b2))
// Ahat = D^-1/2 (A + I) D^-1/2.
// dinv[src] folded into GEMM epilogues (h' = dinv*h, fp16) so aggregation is a
// pure fp16-row gather + sum:  out[v] = dinv[v]*(sum_s h'[s] + h'[v]) + b.

#define TILE 8192  // edges per histogram/scatter workgroup

// per-tile bucket histogram -> Hw[tile][nbuck]   (bucket = dst>>8)
__global__ __launch_bounds__(256) void k_bhist(const int* __restrict__ dst, int E,
                                               int* __restrict__ Hw, int nbuck) {
    __shared__ int h[512];
    int t = threadIdx.x;
    for (int i = t; i < nbuck; i += 256) h[i] = 0;
    __syncthreads();
    int base = blockIdx.x * TILE;
#pragma unroll
    for (int r = 0; r < TILE / 256; ++r) {
        int e = base + r * 256 + t;
        if (e < E) atomicAdd(&h[dst[e] >> 8], 1);
    }
    __syncthreads();
    for (int i = t; i < nbuck; i += 256) Hw[blockIdx.x * nbuck + i] = h[i];
}

// single WG: bucket totals -> exclusive starts; Hw -> per-(tile,bucket) offsets
__global__ __launch_bounds__(512) void k_bscan(int* __restrict__ Hw, int nTiles,
                                               int nbuck, int* __restrict__ bstart) {
    __shared__ int s[512];
    int t = threadIdx.x;
    int total = 0;
    if (t < nbuck)
        for (int tt = 0; tt < nTiles; ++tt) total += Hw[tt * nbuck + t];
    s[t] = total;
    __syncthreads();
    for (int off = 1; off < 512; off <<= 1) {
        int tmp = (t >= off) ? s[t - off] : 0;
        __syncthreads();
        s[t] += tmp;
        __syncthreads();
    }
    int excl = s[t] - total;
    if (t < nbuck) bstart[t] = excl;
    if (t == nbuck - 1) bstart[nbuck] = s[t];  // = E
    __syncthreads();
    if (t < nbuck) {
        int running = excl;
        for (int tt = 0; tt < nTiles; ++tt) {
            int v = Hw[tt * nbuck + t];
            Hw[tt * nbuck + t] = running;
            running += v;
        }
    }
}

// scatter edges bucket-grouped; packed entry = src | (dst&255)<<17  (src<2^17)
__global__ __launch_bounds__(256) void k_bscatter(const int* __restrict__ ei, int E,
                                                  const int* __restrict__ Hw, int nbuck,
                                                  int* __restrict__ ebuf) {
    __shared__ int cur[512];
    int t = threadIdx.x;
    for (int i = t; i < nbuck; i += 256) cur[i] = Hw[blockIdx.x * nbuck + i];
    __syncthreads();
    int base = blockIdx.x * TILE;
#pragma unroll
    for (int r = 0; r < TILE / 256; ++r) {
        int e = base + r * 256 + t;
        if (e < E) {
            int s = ei[e];
            int d = ei[E + e];
            int pos = atomicAdd(&cur[d >> 8], 1);
            ebuf[pos] = s | ((d & 255) << 17);
        }
    }
}

// one WG per bucket (256 nodes): deg/rowstart/dinv + csr fill (local region)
__global__ __launch_bounds__(256) void k_csrfill(const int* __restrict__ ebuf,
                                                 const int* __restrict__ bstart,
                                                 int* __restrict__ csr,
                                                 int* __restrict__ rowstart,
                                                 int* __restrict__ deg,
                                                 float* __restrict__ dinv, int N) {
    __shared__ int lcnt[256];
    __shared__ int lscan[256];
    __shared__ int lcur[256];
    int t = threadIdx.x;
    int nodebase = blockIdx.x << 8;
    int segs = bstart[blockIdx.x];
    int sege = bstart[blockIdx.x + 1];
    lcnt[t] = 0;
    __syncthreads();
    for (int i = segs + t; i < sege; i += 256)
        atomicAdd(&lcnt[((unsigned)ebuf[i]) >> 17], 1);
    __syncthreads();
    int v = lcnt[t];
    lscan[t] = v;
    __syncthreads();
    for (int off = 1; off < 256; off <<= 1) {
        int tmp = (t >= off) ? lscan[t - off] : 0;
        __syncthreads();
        lscan[t] += tmp;
        __syncthreads();
    }
    int excl = lscan[t] - v;
    int node = nodebase + t;
    if (node < N) {
        rowstart[node] = segs + excl;
        deg[node] = v;
        dinv[node] = rsqrtf((float)(v + 1));  // +1 self loop
    }
    lcur[t] = segs + excl;
    __syncthreads();
    for (int i = segs + t; i < sege; i += 256) {
        int pk = ebuf[i];
        int pos = atomicAdd(&lcur[((unsigned)pk) >> 17], 1);
        csr[pos] = pk & 0x1FFFF;
    }
}

// h1p[N][48] = fp16( dinv[r] * (x[N][128] @ W1[128][48]) )
#define G1_BM 64
__global__ __launch_bounds__(192) void k_gemm1(const float* __restrict__ x,
                                               const float* __restrict__ W1,
                                               const float* __restrict__ dinv,
                                               __half* __restrict__ h1p, int N) {
    __shared__ float xs[G1_BM * 132];
    __shared__ float wt[48 * 132];
    int t = threadIdx.x;
    int r0 = blockIdx.x * G1_BM;

    for (int i = t; i < 128 * 48; i += 192) {
        int k = i / 48, c = i % 48;
        wt[c * 132 + k] = W1[i];
    }
    for (int i = t; i < G1_BM * 32; i += 192) {
        int r = i >> 5, kq = i & 31;
        float4 v;
        if (r0 + r < N) v = *(const float4*)(x + (size_t)(r0 + r) * 128 + kq * 4);
        else v = make_float4(0.f, 0.f, 0.f, 0.f);
        *(float4*)(xs + r * 132 + kq * 4) = v;
    }
    __syncthreads();

    int cg = t % 12;
    int rg = t / 12;
    float acc[4][4] = {};
    const float* xa = xs + (rg * 4) * 132;
    const float* wb = wt + (cg * 4) * 132;

    for (int kk = 0; kk < 128; kk += 4) {
        float4 A[4], B[4];
#pragma unroll
        for (int i = 0; i < 4; i++) A[i] = *(const float4*)(xa + i * 132 + kk);
#pragma unroll
        for (int j = 0; j < 4; j++) B[j] = *(const float4*)(wb + j * 132 + kk);
#pragma unroll
        for (int i = 0; i < 4; i++)
#pragma unroll
            for (int j = 0; j < 4; j++)
                acc[i][j] += A[i].x * B[j].x + A[i].y * B[j].y +
                             A[i].z * B[j].z + A[i].w * B[j].w;
    }

#pragma unroll
    for (int i = 0; i < 4; i++) {
        int r = r0 + rg * 4 + i;
        if (r < N) {
            float dr = dinv[r];
            __half2 h01 = __floats2half2_rn(acc[i][0] * dr, acc[i][1] * dr);
            __half2 h23 = __floats2half2_rn(acc[i][2] * dr, acc[i][3] * dr);
            __half* dst = h1p + (size_t)r * 48 + cg * 4;
            *(__half2*)(dst) = h01;
            *(__half2*)(dst + 2) = h23;
        }
    }
}

// layer-1 aggregation: wave per node; edge indices broadcast via shfl;
// fp16 row gather; relu fused.  r1 = relu(dinv[v]*(sum+self)+b1) in f32.
__global__ __launch_bounds__(256) void k_agg1(const __half* __restrict__ h1p,
                                              const int* __restrict__ csr,
                                              const int* __restrict__ rowstart,
                                              const int* __restrict__ deg,
                                              const float* __restrict__ dinv,
                                              const float* __restrict__ b1,
                                              float* __restrict__ r1, int N) {
    int wave = threadIdx.x >> 6;
    int lane = threadIdx.x & 63;
    int v = blockIdx.x * 4 + wave;
    if (v >= N) return;
    int f = lane < 48 ? lane : 47;

    int start = rowstart[v];
    int d = deg[v];
    float dv = dinv[v];
    const int* cs = csr + start;
    float acc = 0.f;

    for (int base = 0; base < d; base += 64) {
        int nb = min(64, d - base);
        int sreg = (base + lane < d) ? cs[base + lane] : 0;
        int e = 0;
        for (; e + 4 <= nb; e += 4) {
            int s0 = __shfl(sreg, e);
            int s1 = __shfl(sreg, e + 1);
            int s2 = __shfl(sreg, e + 2);
            int s3 = __shfl(sreg, e + 3);
            float v0 = __half2float(h1p[(size_t)s0 * 48 + f]);
            float v1 = __half2float(h1p[(size_t)s1 * 48 + f]);
            float v2 = __half2float(h1p[(size_t)s2 * 48 + f]);
            float v3 = __half2float(h1p[(size_t)s3 * 48 + f]);
            acc += v0;
            acc += v1;
            acc += v2;
            acc += v3;
        }
        for (; e < nb; ++e) {
            int s = __shfl(sreg, e);
            acc += __half2float(h1p[(size_t)s * 48 + f]);
        }
    }
    acc += __half2float(h1p[(size_t)v * 48 + f]);  // self (dinv folded)
    float outv = fmaxf(dv * acc + b1[f], 0.f);
    if (lane < 48) r1[(size_t)v * 48 + lane] = outv;
}

// h2p[N][16] = fp16( dinv[row] * (r1[N][48] @ W2[48][16]) )
__global__ __launch_bounds__(256) void k_gemm2(const float* __restrict__ r1,
                                               const float* __restrict__ W2,
                                               const float* __restrict__ dinv,
                                               __half* __restrict__ h2p, int N) {
    __shared__ float w2s[48 * 16];
    int t = threadIdx.x;
    for (int i = t; i < 768; i += 256) w2s[i] = W2[i];
    __syncthreads();
    int flat = blockIdx.x * 256 + t;
    int row = flat >> 2;
    int cg = (flat & 3) * 4;
    if (row >= N) return;
    float4 acc = make_float4(0.f, 0.f, 0.f, 0.f);
    const float* xr = r1 + (size_t)row * 48;
    for (int kk = 0; kk < 48; kk += 4) {
        float4 a = *(const float4*)(xr + kk);
#pragma unroll
        for (int j = 0; j < 4; j++) {
            float av = (j == 0) ? a.x : (j == 1) ? a.y : (j == 2) ? a.z : a.w;
            float4 b = *(const float4*)(w2s + (kk + j) * 16 + cg);
            acc.x += av * b.x;
            acc.y += av * b.y;
            acc.z += av * b.z;
            acc.w += av * b.w;
        }
    }
    float dr = dinv[row];
    __half2 h01 = __floats2half2_rn(acc.x * dr, acc.y * dr);
    __half2 h23 = __floats2half2_rn(acc.z * dr, acc.w * dr);
    __half* dst = h2p + (size_t)row * 16 + cg;
    *(__half2*)(dst) = h01;
    *(__half2*)(dst + 2) = h23;
}

// layer-2 aggregation + bias + relu + 16-wide softmax. 4 nodes per wave.
__global__ __launch_bounds__(256) void k_agg2(const __half* __restrict__ h2p,
                                              const int* __restrict__ csr,
                                              const int* __restrict__ rowstart,
                                              const int* __restrict__ deg,
                                              const float* __restrict__ dinv,
                                              const float* __restrict__ b2,
                                              float* __restrict__ out, int N) {
    int tid = threadIdx.x;
    int lane = tid & 63;
    int g = lane >> 4;
    int f = lane & 15;
    int v = blockIdx.x * 16 + (tid >> 6) * 4 + g;
    if (v >= N) return;

    int start = rowstart[v];
    int d = deg[v];
    float dv = dinv[v];
    const int* cs = csr + start;
    float acc = 0.f;

    for (int base = 0; base < d; base += 16) {
        int nb = min(16, d - base);
        int sreg = (base + f < d) ? cs[base + f] : 0;
        int e = 0;
        for (; e + 4 <= nb; e += 4) {
            int s0 = __shfl(sreg, e, 16);
            int s1 = __shfl(sreg, e + 1, 16);
            int s2 = __shfl(sreg, e + 2, 16);
            int s3 = __shfl(sreg, e + 3, 16);
            acc += __half2float(h2p[(size_t)s0 * 16 + f]);
            acc += __half2float(h2p[(size_t)s1 * 16 + f]);
            acc += __half2float(h2p[(size_t)s2 * 16 + f]);
            acc += __half2float(h2p[(size_t)s3 * 16 + f]);
        }
        for (; e < nb; ++e) {
            int s = __shfl(sreg, e, 16);
            acc += __half2float(h2p[(size_t)s * 16 + f]);
        }
    }
    acc += __half2float(h2p[(size_t)v * 16 + f]);  // self
    float z = fmaxf(dv * acc + b2[f], 0.f);

    float m = z;
    m = fmaxf(m, __shfl_xor(m, 1));
    m = fmaxf(m, __shfl_xor(m, 2));
    m = fmaxf(m, __shfl_xor(m, 4));
    m = fmaxf(m, __shfl_xor(m, 8));
    float p = __expf(z - m);
    float ssum = p;
    ssum += __shfl_xor(ssum, 1);
    ssum += __shfl_xor(ssum, 2);
    ssum += __shfl_xor(ssum, 4);
    ssum += __shfl_xor(ssum, 8);
    out[(size_t)v * 16 + f] = p / ssum;
}

extern "C" void kernel_launch(void* const* d_in, const int* in_sizes, int n_in,
                              void* d_out, int out_size, void* d_ws, size_t ws_size,
                              hipStream_t stream) {
    const float* x  = (const float*)d_in[0];
    const int*   ei = (const int*)d_in[1];
    const float* W1 = (const float*)d_in[2];
    const float* b1 = (const float*)d_in[3];
    const float* W2 = (const float*)d_in[4];
    const float* b2 = (const float*)d_in[5];
    float* out = (float*)d_out;

    int N = in_sizes[0] / 128;
    int E = in_sizes[1] / 2;
    int NBK = (N + 255) >> 8;
    int nTiles = (E + TILE - 1) / TILE;

    char* p = (char*)d_ws;
    auto alloc = [&](size_t bytes) -> char* {
        char* q = p;
        p += (bytes + 255) & ~(size_t)255;
        return q;
    };
    int*    deg      = (int*)alloc((size_t)N * 4);
    int*    rowstart = (int*)alloc((size_t)N * 4);
    float*  dinv     = (float*)alloc((size_t)N * 4);
    int*    bstart   = (int*)alloc((size_t)(NBK + 1) * 4);
    int*    Hw       = (int*)alloc((size_t)nTiles * NBK * 4);
    int*    csr      = (int*)alloc((size_t)E * 4);
    // ebuf (E*4) dead after k_csrfill; h1p (N*48*2) overlays it; h2p after agg1.
    size_t  ovl_sz   = (size_t)N * 48 * 2 > (size_t)E * 4 ? (size_t)N * 48 * 2
                                                          : (size_t)E * 4;
    char*   ovl      = alloc(ovl_sz);
    int*    ebuf     = (int*)ovl;
    __half* h1p      = (__half*)ovl;
    float*  r1       = (float*)alloc((size_t)N * 48 * 4);
    __half* h2p      = h1p;  // h1p dead after k_agg1

    hipLaunchKernelGGL(k_bhist, dim3(nTiles), dim3(256), 0, stream, ei + E, E, Hw, NBK);
    hipLaunchKernelGGL(k_bscan, dim3(1), dim3(512), 0, stream, Hw, nTiles, NBK, bstart);
    hipLaunchKernelGGL(k_bscatter, dim3(nTiles), dim3(256), 0, stream, ei, E, Hw, NBK, ebuf);
    hipLaunchKernelGGL(k_csrfill, dim3(NBK), dim3(256), 0, stream,
                       ebuf, bstart, csr, rowstart, deg, dinv, N);
    hipLaunchKernelGGL(k_gemm1, dim3((N + G1_BM - 1) / G1_BM), dim3(192), 0, stream,
                       x, W1, dinv, h1p, N);
    hipLaunchKernelGGL(k_agg1, dim3((N + 3) / 4), dim3(256), 0, stream,
                       h1p, csr, rowstart, deg, dinv, b1, r1, N);
    hipLaunchKernelGGL(k_gemm2, dim3((N * 4 + 255) / 256), dim3(256), 0, stream,
                       r1, W2, dinv, h2p, N);
    hipLaunchKernelGGL(k_agg2, dim3((N + 15) / 16), dim3(256), 0, stream,
                       h2p, csr, rowstart, deg, dinv, b2, out, N);
}

// Round 4
// 182.679 us; speedup vs baseline: 2.0102x; 1.3346x over previous
//
#include <hip/hip_runtime.h>
#include <hip/hip_bf16.h>
#include <hip/hip_fp16.h>

// GCN 2-layer: h1 = relu(Ahat (x@W1) + b1); out = softmax(relu(Ahat (h1@W2) + b2))
// Ahat = D^-1/2 (A + I) D^-1/2.
// dinv[src] folded into GEMM epilogues (h' = dinv*h, fp16) so aggregation is a
// pure fp16-row gather + sum:  out[v] = dinv[v]*(sum_s h'[s] + h'[v]) + b.
// CSR build: bucketed counting sort (bucket = dst>>8), scan parallelized
// wave-per-bucket (old single-WG scan was 73us of serialized load latency).

#define TILE 8192  // edges per histogram/scatter workgroup

// per-tile bucket histogram -> Hw[tile][nbuck]   (bucket = dst>>8)
__global__ __launch_bounds__(256) void k_bhist(const int* __restrict__ dst, int E,
                                               int* __restrict__ Hw, int nbuck) {
    __shared__ int h[512];
    int t = threadIdx.x;
    for (int i = t; i < nbuck; i += 256) h[i] = 0;
    __syncthreads();
    int base = blockIdx.x * TILE;
#pragma unroll
    for (int r = 0; r < TILE / 256; ++r) {
        int e = base + r * 256 + t;
        if (e < E) atomicAdd(&h[dst[e] >> 8], 1);
    }
    __syncthreads();
    for (int i = t; i < nbuck; i += 256) Hw[blockIdx.x * nbuck + i] = h[i];
}

// one wave per bucket: column sum of Hw -> btot[b]
__global__ __launch_bounds__(256) void k_bsum(const int* __restrict__ Hw, int nTiles,
                                              int nbuck, int* __restrict__ btot) {
    int wid = (blockIdx.x * 256 + threadIdx.x) >> 6;
    int lane = threadIdx.x & 63;
    if (wid >= nbuck) return;
    int sum = 0;
    for (int tt = lane; tt < nTiles; tt += 64) sum += Hw[tt * nbuck + wid];
#pragma unroll
    for (int off = 32; off; off >>= 1) sum += __shfl_down(sum, off);
    if (lane == 0) btot[wid] = sum;
}

// single small block: exclusive scan of bucket totals -> bstart (nbuck <= 512)
__global__ __launch_bounds__(512) void k_bscan2(const int* __restrict__ btot, int nbuck,
                                                int* __restrict__ bstart) {
    __shared__ int s[512];
    int t = threadIdx.x;
    int v = (t < nbuck) ? btot[t] : 0;
    s[t] = v;
    __syncthreads();
    for (int off = 1; off < 512; off <<= 1) {
        int tmp = (t >= off) ? s[t - off] : 0;
        __syncthreads();
        s[t] += tmp;
        __syncthreads();
    }
    if (t < nbuck) bstart[t] = s[t] - v;
    if (t == nbuck - 1) bstart[nbuck] = s[t];  // = E
}

// one wave per bucket: Hw column -> absolute per-(tile,bucket) offsets.
// wave-scan per 64-tile chunk; serial carry only once per chunk.
__global__ __launch_bounds__(256) void k_boff(int* __restrict__ Hw, int nTiles,
                                              int nbuck, const int* __restrict__ bstart) {
    int wid = (blockIdx.x * 256 + threadIdx.x) >> 6;
    int lane = threadIdx.x & 63;
    if (wid >= nbuck) return;
    int running = bstart[wid];
    for (int chunk = 0; chunk < nTiles; chunk += 64) {
        int tt = chunk + lane;
        int v = (tt < nTiles) ? Hw[tt * nbuck + wid] : 0;
        int incl = v;
#pragma unroll
        for (int off = 1; off < 64; off <<= 1) {
            int u = __shfl_up(incl, off);
            if (lane >= off) incl += u;
        }
        if (tt < nTiles) Hw[tt * nbuck + wid] = running + (incl - v);
        running += __shfl(incl, 63);
    }
}

// scatter edges bucket-grouped; packed entry = src | (dst&255)<<17  (src<2^17)
__global__ __launch_bounds__(256) void k_bscatter(const int* __restrict__ ei, int E,
                                                  const int* __restrict__ Hw, int nbuck,
                                                  int* __restrict__ ebuf) {
    __shared__ int cur[512];
    int t = threadIdx.x;
    for (int i = t; i < nbuck; i += 256) cur[i] = Hw[blockIdx.x * nbuck + i];
    __syncthreads();
    int base = blockIdx.x * TILE;
#pragma unroll
    for (int r = 0; r < TILE / 256; ++r) {
        int e = base + r * 256 + t;
        if (e < E) {
            int s = ei[e];
            int d = ei[E + e];
            int pos = atomicAdd(&cur[d >> 8], 1);
            ebuf[pos] = s | ((d & 255) << 17);
        }
    }
}

// one WG per bucket (256 nodes): deg/rowstart/dinv + csr fill (local region)
__global__ __launch_bounds__(256) void k_csrfill(const int* __restrict__ ebuf,
                                                 const int* __restrict__ bstart,
                                                 int* __restrict__ csr,
                                                 int* __restrict__ rowstart,
                                                 int* __restrict__ deg,
                                                 float* __restrict__ dinv, int N) {
    __shared__ int lcnt[256];
    __shared__ int lscan[256];
    __shared__ int lcur[256];
    int t = threadIdx.x;
    int nodebase = blockIdx.x << 8;
    int segs = bstart[blockIdx.x];
    int sege = bstart[blockIdx.x + 1];
    lcnt[t] = 0;
    __syncthreads();
    for (int i = segs + t; i < sege; i += 256)
        atomicAdd(&lcnt[((unsigned)ebuf[i]) >> 17], 1);
    __syncthreads();
    int v = lcnt[t];
    lscan[t] = v;
    __syncthreads();
    for (int off = 1; off < 256; off <<= 1) {
        int tmp = (t >= off) ? lscan[t - off] : 0;
        __syncthreads();
        lscan[t] += tmp;
        __syncthreads();
    }
    int excl = lscan[t] - v;
    int node = nodebase + t;
    if (node < N) {
        rowstart[node] = segs + excl;
        deg[node] = v;
        dinv[node] = rsqrtf((float)(v + 1));  // +1 self loop
    }
    lcur[t] = segs + excl;
    __syncthreads();
    for (int i = segs + t; i < sege; i += 256) {
        int pk = ebuf[i];
        int pos = atomicAdd(&lcur[((unsigned)pk) >> 17], 1);
        csr[pos] = pk & 0x1FFFF;
    }
}

// h1p[N][48] = fp16( dinv[r] * (x[N][128] @ W1[128][48]) )
#define G1_BM 64
__global__ __launch_bounds__(192) void k_gemm1(const float* __restrict__ x,
                                               const float* __restrict__ W1,
                                               const float* __restrict__ dinv,
                                               __half* __restrict__ h1p, int N) {
    __shared__ float xs[G1_BM * 132];
    __shared__ float wt[48 * 132];
    int t = threadIdx.x;
    int r0 = blockIdx.x * G1_BM;

    for (int i = t; i < 128 * 48; i += 192) {
        int k = i / 48, c = i % 48;
        wt[c * 132 + k] = W1[i];
    }
    for (int i = t; i < G1_BM * 32; i += 192) {
        int r = i >> 5, kq = i & 31;
        float4 v;
        if (r0 + r < N) v = *(const float4*)(x + (size_t)(r0 + r) * 128 + kq * 4);
        else v = make_float4(0.f, 0.f, 0.f, 0.f);
        *(float4*)(xs + r * 132 + kq * 4) = v;
    }
    __syncthreads();

    int cg = t % 12;
    int rg = t / 12;
    float acc[4][4] = {};
    const float* xa = xs + (rg * 4) * 132;
    const float* wb = wt + (cg * 4) * 132;

    for (int kk = 0; kk < 128; kk += 4) {
        float4 A[4], B[4];
#pragma unroll
        for (int i = 0; i < 4; i++) A[i] = *(const float4*)(xa + i * 132 + kk);
#pragma unroll
        for (int j = 0; j < 4; j++) B[j] = *(const float4*)(wb + j * 132 + kk);
#pragma unroll
        for (int i = 0; i < 4; i++)
#pragma unroll
            for (int j = 0; j < 4; j++)
                acc[i][j] += A[i].x * B[j].x + A[i].y * B[j].y +
                             A[i].z * B[j].z + A[i].w * B[j].w;
    }

#pragma unroll
    for (int i = 0; i < 4; i++) {
        int r = r0 + rg * 4 + i;
        if (r < N) {
            float dr = dinv[r];
            __half2 h01 = __floats2half2_rn(acc[i][0] * dr, acc[i][1] * dr);
            __half2 h23 = __floats2half2_rn(acc[i][2] * dr, acc[i][3] * dr);
            __half* dst = h1p + (size_t)r * 48 + cg * 4;
            *(__half2*)(dst) = h01;
            *(__half2*)(dst + 2) = h23;
        }
    }
}

// layer-1 aggregation: wave per node; edge indices broadcast via shfl;
// fp16 row gather; relu fused.  r1 = relu(dinv[v]*(sum+self)+b1) in f32.
__global__ __launch_bounds__(256) void k_agg1(const __half* __restrict__ h1p,
                                              const int* __restrict__ csr,
                                              const int* __restrict__ rowstart,
                                              const int* __restrict__ deg,
                                              const float* __restrict__ dinv,
                                              const float* __restrict__ b1,
                                              float* __restrict__ r1, int N) {
    int wave = threadIdx.x >> 6;
    int lane = threadIdx.x & 63;
    int v = blockIdx.x * 4 + wave;
    if (v >= N) return;
    int f = lane < 48 ? lane : 47;

    int start = rowstart[v];
    int d = deg[v];
    float dv = dinv[v];
    const int* cs = csr + start;
    float acc = 0.f;

    for (int base = 0; base < d; base += 64) {
        int nb = min(64, d - base);
        int sreg = (base + lane < d) ? cs[base + lane] : 0;
        int e = 0;
        for (; e + 4 <= nb; e += 4) {
            int s0 = __shfl(sreg, e);
            int s1 = __shfl(sreg, e + 1);
            int s2 = __shfl(sreg, e + 2);
            int s3 = __shfl(sreg, e + 3);
            float v0 = __half2float(h1p[(size_t)s0 * 48 + f]);
            float v1 = __half2float(h1p[(size_t)s1 * 48 + f]);
            float v2 = __half2float(h1p[(size_t)s2 * 48 + f]);
            float v3 = __half2float(h1p[(size_t)s3 * 48 + f]);
            acc += v0;
            acc += v1;
            acc += v2;
            acc += v3;
        }
        for (; e < nb; ++e) {
            int s = __shfl(sreg, e);
            acc += __half2float(h1p[(size_t)s * 48 + f]);
        }
    }
    acc += __half2float(h1p[(size_t)v * 48 + f]);  // self (dinv folded)
    float outv = fmaxf(dv * acc + b1[f], 0.f);
    if (lane < 48) r1[(size_t)v * 48 + lane] = outv;
}

// h2p[N][16] = fp16( dinv[row] * (r1[N][48] @ W2[48][16]) )
__global__ __launch_bounds__(256) void k_gemm2(const float* __restrict__ r1,
                                               const float* __restrict__ W2,
                                               const float* __restrict__ dinv,
                                               __half* __restrict__ h2p, int N) {
    __shared__ float w2s[48 * 16];
    int t = threadIdx.x;
    for (int i = t; i < 768; i += 256) w2s[i] = W2[i];
    __syncthreads();
    int flat = blockIdx.x * 256 + t;
    int row = flat >> 2;
    int cg = (flat & 3) * 4;
    if (row >= N) return;
    float4 acc = make_float4(0.f, 0.f, 0.f, 0.f);
    const float* xr = r1 + (size_t)row * 48;
    for (int kk = 0; kk < 48; kk += 4) {
        float4 a = *(const float4*)(xr + kk);
#pragma unroll
        for (int j = 0; j < 4; j++) {
            float av = (j == 0) ? a.x : (j == 1) ? a.y : (j == 2) ? a.z : a.w;
            float4 b = *(const float4*)(w2s + (kk + j) * 16 + cg);
            acc.x += av * b.x;
            acc.y += av * b.y;
            acc.z += av * b.z;
            acc.w += av * b.w;
        }
    }
    float dr = dinv[row];
    __half2 h01 = __floats2half2_rn(acc.x * dr, acc.y * dr);
    __half2 h23 = __floats2half2_rn(acc.z * dr, acc.w * dr);
    __half* dst = h2p + (size_t)row * 16 + cg;
    *(__half2*)(dst) = h01;
    *(__half2*)(dst + 2) = h23;
}

// layer-2 aggregation + bias + relu + 16-wide softmax. 4 nodes per wave.
__global__ __launch_bounds__(256) void k_agg2(const __half* __restrict__ h2p,
                                              const int* __restrict__ csr,
                                              const int* __restrict__ rowstart,
                                              const int* __restrict__ deg,
                                              const float* __restrict__ dinv,
                                              const float* __restrict__ b2,
                                              float* __restrict__ out, int N) {
    int tid = threadIdx.x;
    int lane = tid & 63;
    int g = lane >> 4;
    int f = lane & 15;
    int v = blockIdx.x * 16 + (tid >> 6) * 4 + g;
    if (v >= N) return;

    int start = rowstart[v];
    int d = deg[v];
    float dv = dinv[v];
    const int* cs = csr + start;
    float acc = 0.f;

    for (int base = 0; base < d; base += 16) {
        int nb = min(16, d - base);
        int sreg = (base + f < d) ? cs[base + f] : 0;
        int e = 0;
        for (; e + 4 <= nb; e += 4) {
            int s0 = __shfl(sreg, e, 16);
            int s1 = __shfl(sreg, e + 1, 16);
            int s2 = __shfl(sreg, e + 2, 16);
            int s3 = __shfl(sreg, e + 3, 16);
            acc += __half2float(h2p[(size_t)s0 * 16 + f]);
            acc += __half2float(h2p[(size_t)s1 * 16 + f]);
            acc += __half2float(h2p[(size_t)s2 * 16 + f]);
            acc += __half2float(h2p[(size_t)s3 * 16 + f]);
        }
        for (; e < nb; ++e) {
            int s = __shfl(sreg, e, 16);
            acc += __half2float(h2p[(size_t)s * 16 + f]);
        }
    }
    acc += __half2float(h2p[(size_t)v * 16 + f]);  // self
    float z = fmaxf(dv * acc + b2[f], 0.f);

    float m = z;
    m = fmaxf(m, __shfl_xor(m, 1));
    m = fmaxf(m, __shfl_xor(m, 2));
    m = fmaxf(m, __shfl_xor(m, 4));
    m = fmaxf(m, __shfl_xor(m, 8));
    float p = __expf(z - m);
    float ssum = p;
    ssum += __shfl_xor(ssum, 1);
    ssum += __shfl_xor(ssum, 2);
    ssum += __shfl_xor(ssum, 4);
    ssum += __shfl_xor(ssum, 8);
    out[(size_t)v * 16 + f] = p / ssum;
}

extern "C" void kernel_launch(void* const* d_in, const int* in_sizes, int n_in,
                              void* d_out, int out_size, void* d_ws, size_t ws_size,
                              hipStream_t stream) {
    const float* x  = (const float*)d_in[0];
    const int*   ei = (const int*)d_in[1];
    const float* W1 = (const float*)d_in[2];
    const float* b1 = (const float*)d_in[3];
    const float* W2 = (const float*)d_in[4];
    const float* b2 = (const float*)d_in[5];
    float* out = (float*)d_out;

    int N = in_sizes[0] / 128;
    int E = in_sizes[1] / 2;
    int NBK = (N + 255) >> 8;
    int nTiles = (E + TILE - 1) / TILE;

    char* p = (char*)d_ws;
    auto alloc = [&](size_t bytes) -> char* {
        char* q = p;
        p += (bytes + 255) & ~(size_t)255;
        return q;
    };
    int*    deg      = (int*)alloc((size_t)N * 4);
    int*    rowstart = (int*)alloc((size_t)N * 4);
    float*  dinv     = (float*)alloc((size_t)N * 4);
    int*    btot     = (int*)alloc((size_t)NBK * 4);
    int*    bstart   = (int*)alloc((size_t)(NBK + 1) * 4);
    int*    Hw       = (int*)alloc((size_t)nTiles * NBK * 4);
    int*    csr      = (int*)alloc((size_t)E * 4);
    // ebuf (E*4) dead after k_csrfill; h1p (N*48*2) overlays it; h2p after agg1.
    size_t  ovl_sz   = (size_t)N * 48 * 2 > (size_t)E * 4 ? (size_t)N * 48 * 2
                                                          : (size_t)E * 4;
    char*   ovl      = alloc(ovl_sz);
    int*    ebuf     = (int*)ovl;
    __half* h1p      = (__half*)ovl;
    float*  r1       = (float*)alloc((size_t)N * 48 * 4);
    __half* h2p      = h1p;  // h1p dead after k_agg1

    int wgBuck = (NBK + 3) / 4;  // 4 waves per 256-thread block

    hipLaunchKernelGGL(k_bhist, dim3(nTiles), dim3(256), 0, stream, ei + E, E, Hw, NBK);
    hipLaunchKernelGGL(k_bsum, dim3(wgBuck), dim3(256), 0, stream, Hw, nTiles, NBK, btot);
    hipLaunchKernelGGL(k_bscan2, dim3(1), dim3(512), 0, stream, btot, NBK, bstart);
    hipLaunchKernelGGL(k_boff, dim3(wgBuck), dim3(256), 0, stream, Hw, nTiles, NBK, bstart);
    hipLaunchKernelGGL(k_bscatter, dim3(nTiles), dim3(256), 0, stream, ei, E, Hw, NBK, ebuf);
    hipLaunchKernelGGL(k_csrfill, dim3(NBK), dim3(256), 0, stream,
                       ebuf, bstart, csr, rowstart, deg, dinv, N);
    hipLaunchKernelGGL(k_gemm1, dim3((N + G1_BM - 1) / G1_BM), dim3(192), 0, stream,
                       x, W1, dinv, h1p, N);
    hipLaunchKernelGGL(k_agg1, dim3((N + 3) / 4), dim3(256), 0, stream,
                       h1p, csr, rowstart, deg, dinv, b1, r1, N);
    hipLaunchKernelGGL(k_gemm2, dim3((N * 4 + 255) / 256), dim3(256), 0, stream,
                       r1, W2, dinv, h2p, N);
    hipLaunchKernelGGL(k_agg2, dim3((N + 15) / 16), dim3(256), 0, stream,
                       h2p, csr, rowstart, deg, dinv, b2, out, N);
}

// Round 5
// 150.534 us; speedup vs baseline: 2.4394x; 1.2135x over previous
//
#include <hip/hip_runtime.h>
#include <hip/hip_bf16.h>
#include <hip/hip_fp16.h>

// GCN 2-layer: h1 = relu(Ahat (x@W1) + b1); out = softmax(relu(Ahat (h1@W2) + b2))
// Ahat = D^-1/2 (A + I) D^-1/2.
// dinv[src] folded into GEMM epilogues (h' = dinv*h, fp16) so aggregation is a
// pure fp16-row gather + sum:  out[v] = dinv[v]*(sum_s h'[s] + h'[v]) + b.
// CSR build: bucketed counting sort (bucket = dst>>8), scan wave-per-bucket.
// gemm1: MFMA fp16 16x16x32 (old f32 tile version: 58KB LDS -> 12.5% occ,
// 3.1M bank conflicts, 60us for a kernel with an 8us memory floor).

#define TILE 8192  // edges per histogram/scatter workgroup

typedef _Float16 half8 __attribute__((ext_vector_type(8)));
typedef float floatx4 __attribute__((ext_vector_type(4)));

// per-tile bucket histogram -> Hw[tile][nbuck]   (bucket = dst>>8)
__global__ __launch_bounds__(256) void k_bhist(const int* __restrict__ dst, int E,
                                               int* __restrict__ Hw, int nbuck) {
    __shared__ int h[512];
    int t = threadIdx.x;
    for (int i = t; i < nbuck; i += 256) h[i] = 0;
    __syncthreads();
    int base = blockIdx.x * TILE;
#pragma unroll
    for (int r = 0; r < TILE / 256; ++r) {
        int e = base + r * 256 + t;
        if (e < E) atomicAdd(&h[dst[e] >> 8], 1);
    }
    __syncthreads();
    for (int i = t; i < nbuck; i += 256) Hw[blockIdx.x * nbuck + i] = h[i];
}

// one wave per bucket: column sum of Hw -> btot[b]
__global__ __launch_bounds__(256) void k_bsum(const int* __restrict__ Hw, int nTiles,
                                              int nbuck, int* __restrict__ btot) {
    int wid = (blockIdx.x * 256 + threadIdx.x) >> 6;
    int lane = threadIdx.x & 63;
    if (wid >= nbuck) return;
    int sum = 0;
    for (int tt = lane; tt < nTiles; tt += 64) sum += Hw[tt * nbuck + wid];
#pragma unroll
    for (int off = 32; off; off >>= 1) sum += __shfl_down(sum, off);
    if (lane == 0) btot[wid] = sum;
}

// single small block: exclusive scan of bucket totals -> bstart (nbuck <= 512)
__global__ __launch_bounds__(512) void k_bscan2(const int* __restrict__ btot, int nbuck,
                                                int* __restrict__ bstart) {
    __shared__ int s[512];
    int t = threadIdx.x;
    int v = (t < nbuck) ? btot[t] : 0;
    s[t] = v;
    __syncthreads();
    for (int off = 1; off < 512; off <<= 1) {
        int tmp = (t >= off) ? s[t - off] : 0;
        __syncthreads();
        s[t] += tmp;
        __syncthreads();
    }
    if (t < nbuck) bstart[t] = s[t] - v;
    if (t == nbuck - 1) bstart[nbuck] = s[t];  // = E
}

// one wave per bucket: Hw column -> absolute per-(tile,bucket) offsets.
__global__ __launch_bounds__(256) void k_boff(int* __restrict__ Hw, int nTiles,
                                              int nbuck, const int* __restrict__ bstart) {
    int wid = (blockIdx.x * 256 + threadIdx.x) >> 6;
    int lane = threadIdx.x & 63;
    if (wid >= nbuck) return;
    int running = bstart[wid];
    for (int chunk = 0; chunk < nTiles; chunk += 64) {
        int tt = chunk + lane;
        int v = (tt < nTiles) ? Hw[tt * nbuck + wid] : 0;
        int incl = v;
#pragma unroll
        for (int off = 1; off < 64; off <<= 1) {
            int u = __shfl_up(incl, off);
            if (lane >= off) incl += u;
        }
        if (tt < nTiles) Hw[tt * nbuck + wid] = running + (incl - v);
        running += __shfl(incl, 63);
    }
}

// scatter edges bucket-grouped; packed entry = src | (dst&255)<<17  (src<2^17)
__global__ __launch_bounds__(256) void k_bscatter(const int* __restrict__ ei, int E,
                                                  const int* __restrict__ Hw, int nbuck,
                                                  int* __restrict__ ebuf) {
    __shared__ int cur[512];
    int t = threadIdx.x;
    for (int i = t; i < nbuck; i += 256) cur[i] = Hw[blockIdx.x * nbuck + i];
    __syncthreads();
    int base = blockIdx.x * TILE;
#pragma unroll
    for (int r = 0; r < TILE / 256; ++r) {
        int e = base + r * 256 + t;
        if (e < E) {
            int s = ei[e];
            int d = ei[E + e];
            int pos = atomicAdd(&cur[d >> 8], 1);
            ebuf[pos] = s | ((d & 255) << 17);
        }
    }
}

// one WG per bucket (256 nodes): deg/rowstart/dinv + csr fill (local region)
__global__ __launch_bounds__(256) void k_csrfill(const int* __restrict__ ebuf,
                                                 const int* __restrict__ bstart,
                                                 int* __restrict__ csr,
                                                 int* __restrict__ rowstart,
                                                 int* __restrict__ deg,
                                                 float* __restrict__ dinv, int N) {
    __shared__ int lcnt[256];
    __shared__ int lscan[256];
    __shared__ int lcur[256];
    int t = threadIdx.x;
    int nodebase = blockIdx.x << 8;
    int segs = bstart[blockIdx.x];
    int sege = bstart[blockIdx.x + 1];
    lcnt[t] = 0;
    __syncthreads();
    for (int i = segs + t; i < sege; i += 256)
        atomicAdd(&lcnt[((unsigned)ebuf[i]) >> 17], 1);
    __syncthreads();
    int v = lcnt[t];
    lscan[t] = v;
    __syncthreads();
    for (int off = 1; off < 256; off <<= 1) {
        int tmp = (t >= off) ? lscan[t - off] : 0;
        __syncthreads();
        lscan[t] += tmp;
        __syncthreads();
    }
    int excl = lscan[t] - v;
    int node = nodebase + t;
    if (node < N) {
        rowstart[node] = segs + excl;
        deg[node] = v;
        dinv[node] = rsqrtf((float)(v + 1));  // +1 self loop
    }
    lcur[t] = segs + excl;
    __syncthreads();
    for (int i = segs + t; i < sege; i += 256) {
        int pk = ebuf[i];
        int pos = atomicAdd(&lcur[((unsigned)pk) >> 17], 1);
        csr[pos] = pk & 0x1FFFF;
    }
}

// h1p[N][48] = fp16( dinv[r] * (x[N][128] @ W1[128][48]) ) via MFMA 16x16x32 f16.
// 4 waves x 16 rows; A-frags straight from global (lane l: row l&15,
// k-seg (l>>4)*8); B-frags from W1-fp16 LDS transposed [48][136].
__global__ __launch_bounds__(256) void k_gemm1(const float* __restrict__ x,
                                               const float* __restrict__ W1,
                                               const float* __restrict__ dinv,
                                               __half* __restrict__ h1p, int N) {
    __shared__ _Float16 wt[48 * 136];
    int t = threadIdx.x;
    for (int i = t; i < 128 * 48; i += 256) {
        int k = i / 48, c = i % 48;
        wt[c * 136 + k] = (_Float16)W1[i];
    }
    __syncthreads();

    int wave = t >> 6, lane = t & 63;
    int g = lane >> 4;                 // k sub-group 0..3
    int rtile = blockIdx.x * 64 + wave * 16;
    int rowA = rtile + (lane & 15);    // A-frag source row
    // clamp OOB rows to a valid address; their outputs are never stored
    const float* xrow = x + (size_t)(rowA < N ? rowA : N - 1) * 128;
    int c0 = lane & 15;

    floatx4 acc[3];
#pragma unroll
    for (int nt = 0; nt < 3; ++nt)
#pragma unroll
        for (int q = 0; q < 4; ++q) acc[nt][q] = 0.f;

#pragma unroll
    for (int kc = 0; kc < 4; ++kc) {
        int k0 = kc * 32 + g * 8;
        float4 a0 = *(const float4*)(xrow + k0);
        float4 a1 = *(const float4*)(xrow + k0 + 4);
        half8 a;
        a[0] = (_Float16)a0.x; a[1] = (_Float16)a0.y;
        a[2] = (_Float16)a0.z; a[3] = (_Float16)a0.w;
        a[4] = (_Float16)a1.x; a[5] = (_Float16)a1.y;
        a[6] = (_Float16)a1.z; a[7] = (_Float16)a1.w;
#pragma unroll
        for (int nt = 0; nt < 3; ++nt) {
            half8 b = *(const half8*)(&wt[(nt * 16 + c0) * 136 + k0]);
            acc[nt] = __builtin_amdgcn_mfma_f32_16x16x32_f16(a, b, acc[nt], 0, 0, 0);
        }
    }

    // D layout: col = lane&15, row = (lane>>4)*4 + reg
    int rbase = rtile + g * 4;
#pragma unroll
    for (int j = 0; j < 4; ++j) {
        int r = rbase + j;
        if (r < N) {
            float dr = dinv[r];
#pragma unroll
            for (int nt = 0; nt < 3; ++nt)
                h1p[(size_t)r * 48 + nt * 16 + c0] = __float2half(acc[nt][j] * dr);
        }
    }
}

// layer-1 aggregation: wave per node; edge indices broadcast via shfl;
// fp16 row gather; relu fused.  r1 = relu(dinv[v]*(sum+self)+b1) in f32.
__global__ __launch_bounds__(256) void k_agg1(const __half* __restrict__ h1p,
                                              const int* __restrict__ csr,
                                              const int* __restrict__ rowstart,
                                              const int* __restrict__ deg,
                                              const float* __restrict__ dinv,
                                              const float* __restrict__ b1,
                                              float* __restrict__ r1, int N) {
    int wave = threadIdx.x >> 6;
    int lane = threadIdx.x & 63;
    int v = blockIdx.x * 4 + wave;
    if (v >= N) return;
    int f = lane < 48 ? lane : 47;

    int start = rowstart[v];
    int d = deg[v];
    float dv = dinv[v];
    const int* cs = csr + start;
    float acc = 0.f;

    for (int base = 0; base < d; base += 64) {
        int nb = min(64, d - base);
        int sreg = (base + lane < d) ? cs[base + lane] : 0;
        int e = 0;
        for (; e + 4 <= nb; e += 4) {
            int s0 = __shfl(sreg, e);
            int s1 = __shfl(sreg, e + 1);
            int s2 = __shfl(sreg, e + 2);
            int s3 = __shfl(sreg, e + 3);
            float v0 = __half2float(h1p[(size_t)s0 * 48 + f]);
            float v1 = __half2float(h1p[(size_t)s1 * 48 + f]);
            float v2 = __half2float(h1p[(size_t)s2 * 48 + f]);
            float v3 = __half2float(h1p[(size_t)s3 * 48 + f]);
            acc += v0;
            acc += v1;
            acc += v2;
            acc += v3;
        }
        for (; e < nb; ++e) {
            int s = __shfl(sreg, e);
            acc += __half2float(h1p[(size_t)s * 48 + f]);
        }
    }
    acc += __half2float(h1p[(size_t)v * 48 + f]);  // self (dinv folded)
    float outv = fmaxf(dv * acc + b1[f], 0.f);
    if (lane < 48) r1[(size_t)v * 48 + lane] = outv;
}

// h2p[N][16] = fp16( dinv[row] * (r1[N][48] @ W2[48][16]) )
__global__ __launch_bounds__(256) void k_gemm2(const float* __restrict__ r1,
                                               const float* __restrict__ W2,
                                               const float* __restrict__ dinv,
                                               __half* __restrict__ h2p, int N) {
    __shared__ float w2s[48 * 16];
    int t = threadIdx.x;
    for (int i = t; i < 768; i += 256) w2s[i] = W2[i];
    __syncthreads();
    int flat = blockIdx.x * 256 + t;
    int row = flat >> 2;
    int cg = (flat & 3) * 4;
    if (row >= N) return;
    float4 acc = make_float4(0.f, 0.f, 0.f, 0.f);
    const float* xr = r1 + (size_t)row * 48;
    for (int kk = 0; kk < 48; kk += 4) {
        float4 a = *(const float4*)(xr + kk);
#pragma unroll
        for (int j = 0; j < 4; j++) {
            float av = (j == 0) ? a.x : (j == 1) ? a.y : (j == 2) ? a.z : a.w;
            float4 b = *(const float4*)(w2s + (kk + j) * 16 + cg);
            acc.x += av * b.x;
            acc.y += av * b.y;
            acc.z += av * b.z;
            acc.w += av * b.w;
        }
    }
    float dr = dinv[row];
    __half2 h01 = __floats2half2_rn(acc.x * dr, acc.y * dr);
    __half2 h23 = __floats2half2_rn(acc.z * dr, acc.w * dr);
    __half* dst = h2p + (size_t)row * 16 + cg;
    *(__half2*)(dst) = h01;
    *(__half2*)(dst + 2) = h23;
}

// layer-2 aggregation + bias + relu + 16-wide softmax. 4 nodes per wave.
__global__ __launch_bounds__(256) void k_agg2(const __half* __restrict__ h2p,
                                              const int* __restrict__ csr,
                                              const int* __restrict__ rowstart,
                                              const int* __restrict__ deg,
                                              const float* __restrict__ dinv,
                                              const float* __restrict__ b2,
                                              float* __restrict__ out, int N) {
    int tid = threadIdx.x;
    int lane = tid & 63;
    int g = lane >> 4;
    int f = lane & 15;
    int v = blockIdx.x * 16 + (tid >> 6) * 4 + g;
    if (v >= N) return;

    int start = rowstart[v];
    int d = deg[v];
    float dv = dinv[v];
    const int* cs = csr + start;
    float acc = 0.f;

    for (int base = 0; base < d; base += 16) {
        int nb = min(16, d - base);
        int sreg = (base + f < d) ? cs[base + f] : 0;
        int e = 0;
        for (; e + 4 <= nb; e += 4) {
            int s0 = __shfl(sreg, e, 16);
            int s1 = __shfl(sreg, e + 1, 16);
            int s2 = __shfl(sreg, e + 2, 16);
            int s3 = __shfl(sreg, e + 3, 16);
            acc += __half2float(h2p[(size_t)s0 * 16 + f]);
            acc += __half2float(h2p[(size_t)s1 * 16 + f]);
            acc += __half2float(h2p[(size_t)s2 * 16 + f]);
            acc += __half2float(h2p[(size_t)s3 * 16 + f]);
        }
        for (; e < nb; ++e) {
            int s = __shfl(sreg, e, 16);
            acc += __half2float(h2p[(size_t)s * 16 + f]);
        }
    }
    acc += __half2float(h2p[(size_t)v * 16 + f]);  // self
    float z = fmaxf(dv * acc + b2[f], 0.f);

    float m = z;
    m = fmaxf(m, __shfl_xor(m, 1));
    m = fmaxf(m, __shfl_xor(m, 2));
    m = fmaxf(m, __shfl_xor(m, 4));
    m = fmaxf(m, __shfl_xor(m, 8));
    float p = __expf(z - m);
    float ssum = p;
    ssum += __shfl_xor(ssum, 1);
    ssum += __shfl_xor(ssum, 2);
    ssum += __shfl_xor(ssum, 4);
    ssum += __shfl_xor(ssum, 8);
    out[(size_t)v * 16 + f] = p / ssum;
}

extern "C" void kernel_launch(void* const* d_in, const int* in_sizes, int n_in,
                              void* d_out, int out_size, void* d_ws, size_t ws_size,
                              hipStream_t stream) {
    const float* x  = (const float*)d_in[0];
    const int*   ei = (const int*)d_in[1];
    const float* W1 = (const float*)d_in[2];
    const float* b1 = (const float*)d_in[3];
    const float* W2 = (const float*)d_in[4];
    const float* b2 = (const float*)d_in[5];
    float* out = (float*)d_out;

    int N = in_sizes[0] / 128;
    int E = in_sizes[1] / 2;
    int NBK = (N + 255) >> 8;
    int nTiles = (E + TILE - 1) / TILE;

    char* p = (char*)d_ws;
    auto alloc = [&](size_t bytes) -> char* {
        char* q = p;
        p += (bytes + 255) & ~(size_t)255;
        return q;
    };
    int*    deg      = (int*)alloc((size_t)N * 4);
    int*    rowstart = (int*)alloc((size_t)N * 4);
    float*  dinv     = (float*)alloc((size_t)N * 4);
    int*    btot     = (int*)alloc((size_t)NBK * 4);
    int*    bstart   = (int*)alloc((size_t)(NBK + 1) * 4);
    int*    Hw       = (int*)alloc((size_t)nTiles * NBK * 4);
    int*    csr      = (int*)alloc((size_t)E * 4);
    // ebuf (E*4) dead after k_csrfill; h1p (N*48*2) overlays it; h2p after agg1.
    size_t  ovl_sz   = (size_t)N * 48 * 2 > (size_t)E * 4 ? (size_t)N * 48 * 2
                                                          : (size_t)E * 4;
    char*   ovl      = alloc(ovl_sz);
    int*    ebuf     = (int*)ovl;
    __half* h1p      = (__half*)ovl;
    float*  r1       = (float*)alloc((size_t)N * 48 * 4);
    __half* h2p      = h1p;  // h1p dead after k_agg1

    int wgBuck = (NBK + 3) / 4;  // 4 waves per 256-thread block

    hipLaunchKernelGGL(k_bhist, dim3(nTiles), dim3(256), 0, stream, ei + E, E, Hw, NBK);
    hipLaunchKernelGGL(k_bsum, dim3(wgBuck), dim3(256), 0, stream, Hw, nTiles, NBK, btot);
    hipLaunchKernelGGL(k_bscan2, dim3(1), dim3(512), 0, stream, btot, NBK, bstart);
    hipLaunchKernelGGL(k_boff, dim3(wgBuck), dim3(256), 0, stream, Hw, nTiles, NBK, bstart);
    hipLaunchKernelGGL(k_bscatter, dim3(nTiles), dim3(256), 0, stream, ei, E, Hw, NBK, ebuf);
    hipLaunchKernelGGL(k_csrfill, dim3(NBK), dim3(256), 0, stream,
                       ebuf, bstart, csr, rowstart, deg, dinv, N);
    hipLaunchKernelGGL(k_gemm1, dim3((N + 63) / 64), dim3(256), 0, stream,
                       x, W1, dinv, h1p, N);
    hipLaunchKernelGGL(k_agg1, dim3((N + 3) / 4), dim3(256), 0, stream,
                       h1p, csr, rowstart, deg, dinv, b1, r1, N);
    hipLaunchKernelGGL(k_gemm2, dim3((N * 4 + 255) / 256), dim3(256), 0, stream,
                       r1, W2, dinv, h2p, N);
    hipLaunchKernelGGL(k_agg2, dim3((N + 15) / 16), dim3(256), 0, stream,
                       h2p, csr, rowstart, deg, dinv, b2, out, N);
}

// Round 6
// 147.984 us; speedup vs baseline: 2.4815x; 1.0172x over previous
//
#include <hip/hip_runtime.h>
#include <hip/hip_bf16.h>
#include <hip/hip_fp16.h>

// GCN 2-layer: h1 = relu(Ahat (x@W1) + b1); out = softmax(relu(Ahat (h1@W2) + b2))
// Ahat = D^-1/2 (A + I) D^-1/2.
// dinv[src] folded into GEMM epilogues (h' = dinv*h, fp16) so aggregation is a
// pure fp16-row gather + sum:  out[v] = dinv[v]*(sum_s h'[s] + h'[v]) + b.
// CSR build: bucketed counting sort (bucket = dst>>8), scan wave-per-bucket.
// gemm1: MFMA fp16 16x16x32. agg kernels: wide-vector gathers (float4/lane,
// 8-16 edges in flight per load instr) — v5's 2B/lane gather was issue-bound
// at 2.3 TB/s with VALUBusy 30%.

#define TILE 8192  // edges per histogram/scatter workgroup

typedef _Float16 half8 __attribute__((ext_vector_type(8)));
typedef float floatx4 __attribute__((ext_vector_type(4)));

// per-tile bucket histogram -> Hw[tile][nbuck]   (bucket = dst>>8)
__global__ __launch_bounds__(256) void k_bhist(const int* __restrict__ dst, int E,
                                               int* __restrict__ Hw, int nbuck) {
    __shared__ int h[512];
    int t = threadIdx.x;
    for (int i = t; i < nbuck; i += 256) h[i] = 0;
    __syncthreads();
    int base = blockIdx.x * TILE;
#pragma unroll
    for (int r = 0; r < TILE / 256; ++r) {
        int e = base + r * 256 + t;
        if (e < E) atomicAdd(&h[dst[e] >> 8], 1);
    }
    __syncthreads();
    for (int i = t; i < nbuck; i += 256) Hw[blockIdx.x * nbuck + i] = h[i];
}

// one wave per bucket: column sum of Hw -> btot[b]
__global__ __launch_bounds__(256) void k_bsum(const int* __restrict__ Hw, int nTiles,
                                              int nbuck, int* __restrict__ btot) {
    int wid = (blockIdx.x * 256 + threadIdx.x) >> 6;
    int lane = threadIdx.x & 63;
    if (wid >= nbuck) return;
    int sum = 0;
    for (int tt = lane; tt < nTiles; tt += 64) sum += Hw[tt * nbuck + wid];
#pragma unroll
    for (int off = 32; off; off >>= 1) sum += __shfl_down(sum, off);
    if (lane == 0) btot[wid] = sum;
}

// single small block: exclusive scan of bucket totals -> bstart (nbuck <= 512)
__global__ __launch_bounds__(512) void k_bscan2(const int* __restrict__ btot, int nbuck,
                                                int* __restrict__ bstart) {
    __shared__ int s[512];
    int t = threadIdx.x;
    int v = (t < nbuck) ? btot[t] : 0;
    s[t] = v;
    __syncthreads();
    for (int off = 1; off < 512; off <<= 1) {
        int tmp = (t >= off) ? s[t - off] : 0;
        __syncthreads();
        s[t] += tmp;
        __syncthreads();
    }
    if (t < nbuck) bstart[t] = s[t] - v;
    if (t == nbuck - 1) bstart[nbuck] = s[t];  // = E
}

// one wave per bucket: Hw column -> absolute per-(tile,bucket) offsets.
__global__ __launch_bounds__(256) void k_boff(int* __restrict__ Hw, int nTiles,
                                              int nbuck, const int* __restrict__ bstart) {
    int wid = (blockIdx.x * 256 + threadIdx.x) >> 6;
    int lane = threadIdx.x & 63;
    if (wid >= nbuck) return;
    int running = bstart[wid];
    for (int chunk = 0; chunk < nTiles; chunk += 64) {
        int tt = chunk + lane;
        int v = (tt < nTiles) ? Hw[tt * nbuck + wid] : 0;
        int incl = v;
#pragma unroll
        for (int off = 1; off < 64; off <<= 1) {
            int u = __shfl_up(incl, off);
            if (lane >= off) incl += u;
        }
        if (tt < nTiles) Hw[tt * nbuck + wid] = running + (incl - v);
        running += __shfl(incl, 63);
    }
}

// scatter edges bucket-grouped; packed entry = src | (dst&255)<<17  (src<2^17)
__global__ __launch_bounds__(256) void k_bscatter(const int* __restrict__ ei, int E,
                                                  const int* __restrict__ Hw, int nbuck,
                                                  int* __restrict__ ebuf) {
    __shared__ int cur[512];
    int t = threadIdx.x;
    for (int i = t; i < nbuck; i += 256) cur[i] = Hw[blockIdx.x * nbuck + i];
    __syncthreads();
    int base = blockIdx.x * TILE;
#pragma unroll
    for (int r = 0; r < TILE / 256; ++r) {
        int e = base + r * 256 + t;
        if (e < E) {
            int s = ei[e];
            int d = ei[E + e];
            int pos = atomicAdd(&cur[d >> 8], 1);
            ebuf[pos] = s | ((d & 255) << 17);
        }
    }
}

// one WG per bucket (256 nodes): deg/rowstart/dinv + csr fill (local region)
__global__ __launch_bounds__(256) void k_csrfill(const int* __restrict__ ebuf,
                                                 const int* __restrict__ bstart,
                                                 int* __restrict__ csr,
                                                 int* __restrict__ rowstart,
                                                 int* __restrict__ deg,
                                                 float* __restrict__ dinv, int N) {
    __shared__ int lcnt[256];
    __shared__ int lscan[256];
    __shared__ int lcur[256];
    int t = threadIdx.x;
    int nodebase = blockIdx.x << 8;
    int segs = bstart[blockIdx.x];
    int sege = bstart[blockIdx.x + 1];
    lcnt[t] = 0;
    __syncthreads();
    for (int i = segs + t; i < sege; i += 256)
        atomicAdd(&lcnt[((unsigned)ebuf[i]) >> 17], 1);
    __syncthreads();
    int v = lcnt[t];
    lscan[t] = v;
    __syncthreads();
    for (int off = 1; off < 256; off <<= 1) {
        int tmp = (t >= off) ? lscan[t - off] : 0;
        __syncthreads();
        lscan[t] += tmp;
        __syncthreads();
    }
    int excl = lscan[t] - v;
    int node = nodebase + t;
    if (node < N) {
        rowstart[node] = segs + excl;
        deg[node] = v;
        dinv[node] = rsqrtf((float)(v + 1));  // +1 self loop
    }
    lcur[t] = segs + excl;
    __syncthreads();
    for (int i = segs + t; i < sege; i += 256) {
        int pk = ebuf[i];
        int pos = atomicAdd(&lcur[((unsigned)pk) >> 17], 1);
        csr[pos] = pk & 0x1FFFF;
    }
}

// h1p[N][48] = fp16( dinv[r] * (x[N][128] @ W1[128][48]) ) via MFMA 16x16x32 f16.
__global__ __launch_bounds__(256) void k_gemm1(const float* __restrict__ x,
                                               const float* __restrict__ W1,
                                               const float* __restrict__ dinv,
                                               __half* __restrict__ h1p, int N) {
    __shared__ _Float16 wt[48 * 136];
    int t = threadIdx.x;
    for (int i = t; i < 128 * 48; i += 256) {
        int k = i / 48, c = i % 48;
        wt[c * 136 + k] = (_Float16)W1[i];
    }
    __syncthreads();

    int wave = t >> 6, lane = t & 63;
    int g = lane >> 4;                 // k sub-group 0..3
    int rtile = blockIdx.x * 64 + wave * 16;
    int rowA = rtile + (lane & 15);    // A-frag source row
    const float* xrow = x + (size_t)(rowA < N ? rowA : N - 1) * 128;
    int c0 = lane & 15;

    floatx4 acc[3];
#pragma unroll
    for (int nt = 0; nt < 3; ++nt)
#pragma unroll
        for (int q = 0; q < 4; ++q) acc[nt][q] = 0.f;

#pragma unroll
    for (int kc = 0; kc < 4; ++kc) {
        int k0 = kc * 32 + g * 8;
        float4 a0 = *(const float4*)(xrow + k0);
        float4 a1 = *(const float4*)(xrow + k0 + 4);
        half8 a;
        a[0] = (_Float16)a0.x; a[1] = (_Float16)a0.y;
        a[2] = (_Float16)a0.z; a[3] = (_Float16)a0.w;
        a[4] = (_Float16)a1.x; a[5] = (_Float16)a1.y;
        a[6] = (_Float16)a1.z; a[7] = (_Float16)a1.w;
#pragma unroll
        for (int nt = 0; nt < 3; ++nt) {
            half8 b = *(const half8*)(&wt[(nt * 16 + c0) * 136 + k0]);
            acc[nt] = __builtin_amdgcn_mfma_f32_16x16x32_f16(a, b, acc[nt], 0, 0, 0);
        }
    }

    // D layout: col = lane&15, row = (lane>>4)*4 + reg
    int rbase = rtile + g * 4;
#pragma unroll
    for (int j = 0; j < 4; ++j) {
        int r = rbase + j;
        if (r < N) {
            float dr = dinv[r];
#pragma unroll
            for (int nt = 0; nt < 3; ++nt)
                h1p[(size_t)r * 48 + nt * 16 + c0] = __float2half(acc[nt][j] * dr);
        }
    }
}

// layer-1 aggregation v2: wave per node; 8 edge-groups x (6 lanes x float4):
// 8 edges / 768B of row payload per load instruction.
__global__ __launch_bounds__(256) void k_agg1(const __half* __restrict__ h1p,
                                              const int* __restrict__ csr,
                                              const int* __restrict__ rowstart,
                                              const int* __restrict__ deg,
                                              const float* __restrict__ dinv,
                                              const float* __restrict__ b1,
                                              float* __restrict__ r1, int N) {
    int wave = threadIdx.x >> 6;
    int lane = threadIdx.x & 63;
    int v = blockIdx.x * 4 + wave;
    if (v >= N) return;
    int grp = lane >> 3;  // edge group 0..7
    int sub = lane & 7;   // subs 0..5 carry features sub*8..sub*8+7

    int start = rowstart[v];
    int d = deg[v];
    float dv = dinv[v];
    const int* cs = csr + start;
    const char* h1b = (const char*)h1p;

    float acc[8] = {0.f, 0.f, 0.f, 0.f, 0.f, 0.f, 0.f, 0.f};

    for (int base = 0; base < d; base += 64) {
        int sreg = (base + lane < d) ? cs[base + lane] : 0;
        int nb = min(64, d - base);
        for (int j = 0; j < 8 && j * 8 < nb; ++j) {
            int s = __shfl(sreg, j * 8 + grp);
            if (j * 8 + grp < nb && sub < 6) {
                float4 rv = *(const float4*)(h1b + (size_t)s * 96 + sub * 16);
                const __half2* hp = (const __half2*)&rv;
#pragma unroll
                for (int q = 0; q < 4; ++q) {
                    float2 f = __half22float2(hp[q]);
                    acc[q * 2] += f.x;
                    acc[q * 2 + 1] += f.y;
                }
            }
        }
    }
    // fold the 8 edge groups (idle sub-lanes hold zeros)
#pragma unroll
    for (int i = 0; i < 8; ++i) {
        acc[i] += __shfl_xor(acc[i], 8);
        acc[i] += __shfl_xor(acc[i], 16);
        acc[i] += __shfl_xor(acc[i], 32);
    }
    if (grp == 0 && sub < 6) {
        float4 sv = *(const float4*)(h1b + (size_t)v * 96 + sub * 16);
        const __half2* hp = (const __half2*)&sv;
        float o[8];
#pragma unroll
        for (int q = 0; q < 4; ++q) {
            float2 f = __half22float2(hp[q]);
            o[q * 2]     = fmaxf(dv * (acc[q * 2] + f.x) + b1[sub * 8 + q * 2], 0.f);
            o[q * 2 + 1] = fmaxf(dv * (acc[q * 2 + 1] + f.y) + b1[sub * 8 + q * 2 + 1], 0.f);
        }
        float4* dst = (float4*)(r1 + (size_t)v * 48 + sub * 8);
        dst[0] = make_float4(o[0], o[1], o[2], o[3]);
        dst[1] = make_float4(o[4], o[5], o[6], o[7]);
    }
}

// h2p[N][16] = fp16( dinv[row] * (r1[N][48] @ W2[48][16]) )
__global__ __launch_bounds__(256) void k_gemm2(const float* __restrict__ r1,
                                               const float* __restrict__ W2,
                                               const float* __restrict__ dinv,
                                               __half* __restrict__ h2p, int N) {
    __shared__ float w2s[48 * 16];
    int t = threadIdx.x;
    for (int i = t; i < 768; i += 256) w2s[i] = W2[i];
    __syncthreads();
    int flat = blockIdx.x * 256 + t;
    int row = flat >> 2;
    int cg = (flat & 3) * 4;
    if (row >= N) return;
    float4 acc = make_float4(0.f, 0.f, 0.f, 0.f);
    const float* xr = r1 + (size_t)row * 48;
    for (int kk = 0; kk < 48; kk += 4) {
        float4 a = *(const float4*)(xr + kk);
#pragma unroll
        for (int j = 0; j < 4; j++) {
            float av = (j == 0) ? a.x : (j == 1) ? a.y : (j == 2) ? a.z : a.w;
            float4 b = *(const float4*)(w2s + (kk + j) * 16 + cg);
            acc.x += av * b.x;
            acc.y += av * b.y;
            acc.z += av * b.z;
            acc.w += av * b.w;
        }
    }
    float dr = dinv[row];
    __half2 h01 = __floats2half2_rn(acc.x * dr, acc.y * dr);
    __half2 h23 = __floats2half2_rn(acc.z * dr, acc.w * dr);
    __half* dst = h2p + (size_t)row * 16 + cg;
    *(__half2*)(dst) = h01;
    *(__half2*)(dst + 2) = h23;
}

// layer-2 aggregation v2: 2 nodes/wave; per half-wave 16 edge-groups x
// (2 lanes x float4) = 16 edges per load instruction. Softmax in sub-lanes.
__global__ __launch_bounds__(256) void k_agg2(const __half* __restrict__ h2p,
                                              const int* __restrict__ csr,
                                              const int* __restrict__ rowstart,
                                              const int* __restrict__ deg,
                                              const float* __restrict__ dinv,
                                              const float* __restrict__ b2,
                                              float* __restrict__ out, int N) {
    int tid = threadIdx.x;
    int lane = tid & 63;
    int hf = lane >> 5;   // node within wave
    int l32 = lane & 31;
    int grp = l32 >> 1;   // edge group 0..15 within half-wave
    int sub = lane & 1;   // features sub*8..sub*8+7
    int v = (blockIdx.x * 4 + (tid >> 6)) * 2 + hf;
    if (v >= N) return;

    int start = rowstart[v];
    int d = deg[v];
    float dv = dinv[v];
    const int* cs = csr + start;
    const char* h2b = (const char*)h2p;

    float acc[8] = {0.f, 0.f, 0.f, 0.f, 0.f, 0.f, 0.f, 0.f};

    for (int base = 0; base < d; base += 32) {
        int sreg = (base + l32 < d) ? cs[base + l32] : 0;
        int nb = min(32, d - base);
        for (int j = 0; j < 2 && j * 16 < nb; ++j) {
            int s = __shfl(sreg, (hf << 5) + j * 16 + grp);
            if (j * 16 + grp < nb) {
                float4 rv = *(const float4*)(h2b + (size_t)s * 32 + sub * 16);
                const __half2* hp = (const __half2*)&rv;
#pragma unroll
                for (int q = 0; q < 4; ++q) {
                    float2 f = __half22float2(hp[q]);
                    acc[q * 2] += f.x;
                    acc[q * 2 + 1] += f.y;
                }
            }
        }
    }
    // fold 16 edge groups within this half-wave
#pragma unroll
    for (int i = 0; i < 8; ++i) {
        acc[i] += __shfl_xor(acc[i], 2);
        acc[i] += __shfl_xor(acc[i], 4);
        acc[i] += __shfl_xor(acc[i], 8);
        acc[i] += __shfl_xor(acc[i], 16);
    }
    if (grp == 0) {
        float4 sv = *(const float4*)(h2b + (size_t)v * 32 + sub * 16);
        const __half2* hp = (const __half2*)&sv;
        float z[8];
#pragma unroll
        for (int q = 0; q < 4; ++q) {
            float2 f = __half22float2(hp[q]);
            z[q * 2]     = fmaxf(dv * (acc[q * 2] + f.x) + b2[sub * 8 + q * 2], 0.f);
            z[q * 2 + 1] = fmaxf(dv * (acc[q * 2 + 1] + f.y) + b2[sub * 8 + q * 2 + 1], 0.f);
        }
        float m8 = z[0];
#pragma unroll
        for (int i = 1; i < 8; ++i) m8 = fmaxf(m8, z[i]);
        float m = fmaxf(m8, __shfl_xor(m8, 1));
        float p[8];
        float s8 = 0.f;
#pragma unroll
        for (int i = 0; i < 8; ++i) { p[i] = __expf(z[i] - m); s8 += p[i]; }
        float inv = 1.f / (s8 + __shfl_xor(s8, 1));
        float4* dst = (float4*)(out + (size_t)v * 16 + sub * 8);
        dst[0] = make_float4(p[0] * inv, p[1] * inv, p[2] * inv, p[3] * inv);
        dst[1] = make_float4(p[4] * inv, p[5] * inv, p[6] * inv, p[7] * inv);
    }
}

extern "C" void kernel_launch(void* const* d_in, const int* in_sizes, int n_in,
                              void* d_out, int out_size, void* d_ws, size_t ws_size,
                              hipStream_t stream) {
    const float* x  = (const float*)d_in[0];
    const int*   ei = (const int*)d_in[1];
    const float* W1 = (const float*)d_in[2];
    const float* b1 = (const float*)d_in[3];
    const float* W2 = (const float*)d_in[4];
    const float* b2 = (const float*)d_in[5];
    float* out = (float*)d_out;

    int N = in_sizes[0] / 128;
    int E = in_sizes[1] / 2;
    int NBK = (N + 255) >> 8;
    int nTiles = (E + TILE - 1) / TILE;

    char* p = (char*)d_ws;
    auto alloc = [&](size_t bytes) -> char* {
        char* q = p;
        p += (bytes + 255) & ~(size_t)255;
        return q;
    };
    int*    deg      = (int*)alloc((size_t)N * 4);
    int*    rowstart = (int*)alloc((size_t)N * 4);
    float*  dinv     = (float*)alloc((size_t)N * 4);
    int*    btot     = (int*)alloc((size_t)NBK * 4);
    int*    bstart   = (int*)alloc((size_t)(NBK + 1) * 4);
    int*    Hw       = (int*)alloc((size_t)nTiles * NBK * 4);
    int*    csr      = (int*)alloc((size_t)E * 4);
    // ebuf (E*4) dead after k_csrfill; h1p (N*48*2) overlays it; h2p after agg1.
    size_t  ovl_sz   = (size_t)N * 48 * 2 > (size_t)E * 4 ? (size_t)N * 48 * 2
                                                          : (size_t)E * 4;
    char*   ovl      = alloc(ovl_sz);
    int*    ebuf     = (int*)ovl;
    __half* h1p      = (__half*)ovl;
    float*  r1       = (float*)alloc((size_t)N * 48 * 4);
    __half* h2p      = h1p;  // h1p dead after k_agg1

    int wgBuck = (NBK + 3) / 4;  // 4 waves per 256-thread block

    hipLaunchKernelGGL(k_bhist, dim3(nTiles), dim3(256), 0, stream, ei + E, E, Hw, NBK);
    hipLaunchKernelGGL(k_bsum, dim3(wgBuck), dim3(256), 0, stream, Hw, nTiles, NBK, btot);
    hipLaunchKernelGGL(k_bscan2, dim3(1), dim3(512), 0, stream, btot, NBK, bstart);
    hipLaunchKernelGGL(k_boff, dim3(wgBuck), dim3(256), 0, stream, Hw, nTiles, NBK, bstart);
    hipLaunchKernelGGL(k_bscatter, dim3(nTiles), dim3(256), 0, stream, ei, E, Hw, NBK, ebuf);
    hipLaunchKernelGGL(k_csrfill, dim3(NBK), dim3(256), 0, stream,
                       ebuf, bstart, csr, rowstart, deg, dinv, N);
    hipLaunchKernelGGL(k_gemm1, dim3((N + 63) / 64), dim3(256), 0, stream,
                       x, W1, dinv, h1p, N);
    hipLaunchKernelGGL(k_agg1, dim3((N + 3) / 4), dim3(256), 0, stream,
                       h1p, csr, rowstart, deg, dinv, b1, r1, N);
    hipLaunchKernelGGL(k_gemm2, dim3((N * 4 + 255) / 256), dim3(256), 0, stream,
                       r1, W2, dinv, h2p, N);
    hipLaunchKernelGGL(k_agg2, dim3((N + 7) / 8), dim3(256), 0, stream,
                       h2p, csr, rowstart, deg, dinv, b2, out, N);
}